// Round 1
// baseline (12404.580 us; speedup 1.0000x reference)
//
#include <hip/hip_runtime.h>

#define NN 100000
#define NE 1200000
#define DD 64
#define EDIM 16
#define NL 3
#define NG 512
#define NC 10

// ---------------------------------------------------------------------------
// prep: Wc[l] = w_edge @ lin_w[l]   (16x64),  bc[l] = b_edge @ lin_w[l] + lin_b[l]
// grid: NL blocks x 1024 threads
__global__ __launch_bounds__(1024) void prep_kernel(
    const float* __restrict__ w_edge, const float* __restrict__ b_edge,
    const float* __restrict__ lin_w, const float* __restrict__ lin_b,
    float* __restrict__ Wc, float* __restrict__ bc)
{
    const int l = blockIdx.x;
    const int tid = threadIdx.x;
    const float* Lw = lin_w + l * 4096;
    const int k = tid >> 6, col = tid & 63;
    float acc = 0.f;
    for (int j = 0; j < 64; ++j) acc = fmaf(w_edge[k*64 + j], Lw[j*64 + col], acc);
    Wc[l*1024 + k*64 + col] = acc;
    if (tid < 64) {
        float a = lin_b[l*64 + tid];
        for (int j = 0; j < 64; ++j) a = fmaf(b_edge[j], Lw[j*64 + tid], a);
        bc[l*64 + tid] = a;
    }
}

// ---------------------------------------------------------------------------
// Generic [nrows,64] @ [64,64] + bias GEMM.
// IN_MODE: 0 = in0, 1 = in0+in1, 2 = relu(in0*scale+shift)
// OUT_RELU: relu on output. OUT_ACCUM: accumulate column sum/sumsq of raw
// (pre-relu) output into bn_sum/bn_sumsq (for training-mode BatchNorm).
template<int IN_MODE, bool OUT_RELU, bool OUT_ACCUM>
__global__ __launch_bounds__(256) void gemm64_kernel(
    const float* __restrict__ in0, const float* __restrict__ in1,
    const float* __restrict__ W, const float* __restrict__ bias,
    const float* __restrict__ scale, const float* __restrict__ shift,
    float* __restrict__ out, int nrows,
    float* __restrict__ bn_sum, float* __restrict__ bn_sumsq)
{
    __shared__ __align__(16) float sIn[64*64];
    __shared__ float sRed[512];
    const int tid = threadIdx.x;
    const int col = tid & 63;
    const int rq  = tid >> 6;
    const int r0  = blockIdx.x * 64;

    // W column in registers (col fixed per thread); coalesced per-k loads.
    float wreg[64];
    #pragma unroll
    for (int k = 0; k < 64; ++k) wreg[k] = W[k*64 + col];
    const float bcol = bias[col];

    // stage 64 input rows (with transform) into LDS
    for (int i = tid; i < 1024; i += 256) {
        const int r  = i >> 4;
        const int c4 = (i & 15) * 4;
        const int gr = r0 + r;
        float4 v = make_float4(0.f, 0.f, 0.f, 0.f);
        if (gr < nrows) {
            v = *(const float4*)(in0 + (size_t)gr*64 + c4);
            if constexpr (IN_MODE == 1) {
                float4 w2 = *(const float4*)(in1 + (size_t)gr*64 + c4);
                v.x += w2.x; v.y += w2.y; v.z += w2.z; v.w += w2.w;
            }
            if constexpr (IN_MODE == 2) {
                float4 s4 = *(const float4*)(scale + c4);
                float4 h4 = *(const float4*)(shift + c4);
                v.x = fmaxf(fmaf(v.x, s4.x, h4.x), 0.f);
                v.y = fmaxf(fmaf(v.y, s4.y, h4.y), 0.f);
                v.z = fmaxf(fmaf(v.z, s4.z, h4.z), 0.f);
                v.w = fmaxf(fmaf(v.w, s4.w, h4.w), 0.f);
            }
        }
        *(float4*)(sIn + r*64 + c4) = v;
    }
    __syncthreads();

    float ps = 0.f, psq = 0.f;
    for (int r = rq; r < 64; r += 4) {
        float acc = bcol;
        #pragma unroll
        for (int k = 0; k < 64; k += 4) {
            float4 a = *(const float4*)(sIn + r*64 + k);
            acc = fmaf(a.x, wreg[k+0], acc);
            acc = fmaf(a.y, wreg[k+1], acc);
            acc = fmaf(a.z, wreg[k+2], acc);
            acc = fmaf(a.w, wreg[k+3], acc);
        }
        const int gr = r0 + r;
        if (gr < nrows) {
            if constexpr (OUT_ACCUM) { ps += acc; psq += acc*acc; }
            out[(size_t)gr*64 + col] = OUT_RELU ? fmaxf(acc, 0.f) : acc;
        }
    }

    if constexpr (OUT_ACCUM) {
        sRed[rq*64 + col]       = ps;
        sRed[256 + rq*64 + col] = psq;
        __syncthreads();
        if (rq == 0) {
            float s = sRed[col] + sRed[64+col] + sRed[128+col] + sRed[192+col];
            float q = sRed[256+col] + sRed[320+col] + sRed[384+col] + sRed[448+col];
            atomicAdd(bn_sum + col, s);
            atomicAdd(bn_sumsq + col, q);
        }
    }
}

// ---------------------------------------------------------------------------
// bn scale/shift from accumulated sums:  y = x*scale + shift
__global__ __launch_bounds__(64) void bn_finalize_kernel(
    const float* __restrict__ sum, const float* __restrict__ sumsq,
    const float* __restrict__ gamma, const float* __restrict__ beta,
    float inv_count, float* __restrict__ scale, float* __restrict__ shift)
{
    const int t = threadIdx.x;
    float mu  = sum[t] * inv_count;
    float var = fmaxf(sumsq[t] * inv_count - mu*mu, 0.f);
    float x = var + 1e-5f;
    float r = rsqrtf(x);
    r = r * (1.5f - 0.5f * x * r * r);   // one Newton step
    float sc = gamma[t] * r;
    scale[t] = sc;
    shift[t] = beta[t] - mu * sc;
}

// ---------------------------------------------------------------------------
// edge kernel: m = relu(h[src] + edge_attr @ Wc + bc); agg[dst] += m (atomics)
__global__ __launch_bounds__(256) void edge_kernel(
    const int* __restrict__ src, const int* __restrict__ dst,
    const float* __restrict__ edge_attr,
    const float* __restrict__ Wc, const float* __restrict__ bc,
    const float* __restrict__ h, float* __restrict__ agg)
{
    __shared__ __align__(16) float sW[16*64];
    __shared__ __align__(16) float sb[64];
    const int tid = threadIdx.x;
    ((float4*)sW)[tid] = ((const float4*)Wc)[tid];        // 256 float4 = 1024 floats
    if (tid < 16) ((float4*)sb)[tid] = ((const float4*)bc)[tid];
    __syncthreads();

    const int e = blockIdx.x * 256 + tid;
    if (e >= NE) return;

    float ea[16];
    const float4* eap = (const float4*)(edge_attr + (size_t)e * 16);
    float4 e0 = eap[0], e1 = eap[1], e2 = eap[2], e3 = eap[3];
    ea[0]=e0.x; ea[1]=e0.y; ea[2]=e0.z; ea[3]=e0.w;
    ea[4]=e1.x; ea[5]=e1.y; ea[6]=e1.z; ea[7]=e1.w;
    ea[8]=e2.x; ea[9]=e2.y; ea[10]=e2.z; ea[11]=e2.w;
    ea[12]=e3.x; ea[13]=e3.y; ea[14]=e3.z; ea[15]=e3.w;

    const int s = src[e], d = dst[e];
    const float* hrow = h + (size_t)s * 64;
    float* arow = agg + (size_t)d * 64;

    #pragma unroll
    for (int c4 = 0; c4 < 16; ++c4) {
        float4 acc = ((const float4*)sb)[c4];
        #pragma unroll
        for (int k = 0; k < 16; ++k) {
            float4 w = *(const float4*)(sW + k*64 + c4*4);
            acc.x = fmaf(ea[k], w.x, acc.x);
            acc.y = fmaf(ea[k], w.y, acc.y);
            acc.z = fmaf(ea[k], w.z, acc.z);
            acc.w = fmaf(ea[k], w.w, acc.w);
        }
        float4 hv = *(const float4*)(hrow + c4*4);
        float m0 = fmaxf(acc.x + hv.x, 0.f);
        float m1 = fmaxf(acc.y + hv.y, 0.f);
        float m2 = fmaxf(acc.z + hv.z, 0.f);
        float m3 = fmaxf(acc.w + hv.w, 0.f);
        atomicAdd(arow + c4*4 + 0, m0);
        atomicAdd(arow + c4*4 + 1, m1);
        atomicAdd(arow + c4*4 + 2, m2);
        atomicAdd(arow + c4*4 + 3, m3);
    }
}

// ---------------------------------------------------------------------------
// global_add_pool: batch is sorted -> one wave per graph, binary-search range
__global__ __launch_bounds__(64) void pool_kernel(
    const float* __restrict__ h, const int* __restrict__ batch,
    float* __restrict__ pooled)
{
    const int g = blockIdx.x;
    const int lane = threadIdx.x;
    int lo = 0, hi = NN;
    while (lo < hi) { int m = (lo + hi) >> 1; if (batch[m] < g) lo = m + 1; else hi = m; }
    const int start = lo;
    hi = NN;
    while (lo < hi) { int m = (lo + hi) >> 1; if (batch[m] < g + 1) lo = m + 1; else hi = m; }
    const int end = lo;
    float acc = 0.f;
    for (int n = start; n < end; ++n) acc += h[(size_t)n*64 + lane];
    pooled[g*64 + lane] = acc;
}

// ---------------------------------------------------------------------------
// final head: out = bn2(hb) @ fo3_w + fo3_b   (no relu before final linear)
__global__ __launch_bounds__(256) void head_final_kernel(
    const float* __restrict__ hb, const float* __restrict__ scale,
    const float* __restrict__ shift, const float* __restrict__ fo3_w,
    const float* __restrict__ fo3_b, float* __restrict__ out)
{
    const int idx = blockIdx.x * 256 + threadIdx.x;
    if (idx >= NG * NC) return;
    const int g = idx / NC, c = idx % NC;
    float acc = fo3_b[c];
    for (int k = 0; k < 64; ++k) {
        float v = fmaf(hb[g*64 + k], scale[k], shift[k]);
        acc = fmaf(v, fo3_w[k*NC + c], acc);
    }
    out[idx] = acc;
}

// ---------------------------------------------------------------------------
extern "C" void kernel_launch(void* const* d_in, const int* in_sizes, int n_in,
                              void* d_out, int out_size, void* d_ws, size_t ws_size,
                              hipStream_t stream) {
    const float* x         = (const float*)d_in[0];
    const int*   edge_index= (const int*)  d_in[1];
    const int*   batch     = (const int*)  d_in[2];
    const float* edge_attr = (const float*)d_in[3];
    const float* w_node    = (const float*)d_in[4];
    const float* b_node    = (const float*)d_in[5];
    const float* w_edge    = (const float*)d_in[6];
    const float* b_edge    = (const float*)d_in[7];
    const float* lin_w     = (const float*)d_in[8];
    const float* lin_b     = (const float*)d_in[9];
    const float* mlp1_w    = (const float*)d_in[10];
    const float* mlp1_b    = (const float*)d_in[11];
    const float* bn1_g     = (const float*)d_in[12];
    const float* bn1_b     = (const float*)d_in[13];
    const float* mlp2_w    = (const float*)d_in[14];
    const float* mlp2_b    = (const float*)d_in[15];
    const float* fo1_w     = (const float*)d_in[16];
    const float* fo1_b     = (const float*)d_in[17];
    const float* fo_bn1_g  = (const float*)d_in[18];
    const float* fo_bn1_b  = (const float*)d_in[19];
    const float* fo2_w     = (const float*)d_in[20];
    const float* fo2_b     = (const float*)d_in[21];
    const float* fo_bn2_g  = (const float*)d_in[22];
    const float* fo_bn2_b  = (const float*)d_in[23];
    const float* fo3_w     = (const float*)d_in[24];
    const float* fo3_b     = (const float*)d_in[25];
    float* out = (float*)d_out;

    char* ws = (char*)d_ws;
    float* h   = (float*)(ws);                       // NN*64 floats (25.6 MB)
    float* agg = (float*)(ws + 25600000);            // NN*64 floats; aliased as t (safe: gemm blocks read-then-write own rows)
    float* sm  = (float*)(ws + 51200000);
    float* Wc       = sm;            // 3072
    float* bc       = sm + 3072;     // 192
    float* scale    = sm + 3264;     // 64
    float* shift    = sm + 3328;     // 64
    float* bn_sum   = sm + 3392;     // 64
    float* bn_sumsq = sm + 3456;     // 64
    float* pooled   = sm + 3520;     // 32768
    float* ha       = sm + 36288;    // 32768
    float* hb       = sm + 69056;    // 32768

    const int* src = edge_index;
    const int* dst = edge_index + NE;
    float* t = agg;   // alias

    const int gemmN_blocks = (NN + 63) / 64;     // 1563
    const int edge_blocks  = (NE + 255) / 256;   // 4688

    prep_kernel<<<NL, 1024, 0, stream>>>(w_edge, b_edge, lin_w, lin_b, Wc, bc);

    // h = x @ w_node + b_node
    gemm64_kernel<0, false, false><<<gemmN_blocks, 256, 0, stream>>>(
        x, nullptr, w_node, b_node, nullptr, nullptr, h, NN, nullptr, nullptr);

    for (int l = 0; l < NL; ++l) {
        hipMemsetAsync(agg, 0, (size_t)NN * 64 * sizeof(float), stream);
        edge_kernel<<<edge_blocks, 256, 0, stream>>>(
            src, dst, edge_attr, Wc + l*1024, bc + l*64, h, agg);
        hipMemsetAsync(bn_sum, 0, 128 * sizeof(float), stream);
        // t = (agg + h) @ mlp1_w + b  (in-place over agg), accumulate BN stats
        gemm64_kernel<1, false, true><<<gemmN_blocks, 256, 0, stream>>>(
            agg, h, mlp1_w + l*4096, mlp1_b + l*64, nullptr, nullptr,
            t, NN, bn_sum, bn_sumsq);
        bn_finalize_kernel<<<1, 64, 0, stream>>>(
            bn_sum, bn_sumsq, bn1_g + l*64, bn1_b + l*64, 1.0f / NN, scale, shift);
        // h = relu( relu(bn(t)) @ mlp2_w + b )
        gemm64_kernel<2, true, false><<<gemmN_blocks, 256, 0, stream>>>(
            t, nullptr, mlp2_w + l*4096, mlp2_b + l*64, scale, shift,
            h, NN, nullptr, nullptr);
    }

    pool_kernel<<<NG, 64, 0, stream>>>(h, batch, pooled);

    // head
    hipMemsetAsync(bn_sum, 0, 128 * sizeof(float), stream);
    gemm64_kernel<0, false, true><<<NG/64, 256, 0, stream>>>(
        pooled, nullptr, fo1_w, fo1_b, nullptr, nullptr, ha, NG, bn_sum, bn_sumsq);
    bn_finalize_kernel<<<1, 64, 0, stream>>>(
        bn_sum, bn_sumsq, fo_bn1_g, fo_bn1_b, 1.0f / NG, scale, shift);
    hipMemsetAsync(bn_sum, 0, 128 * sizeof(float), stream);
    gemm64_kernel<2, false, true><<<NG/64, 256, 0, stream>>>(
        ha, nullptr, fo2_w, fo2_b, scale, shift, hb, NG, bn_sum, bn_sumsq);
    bn_finalize_kernel<<<1, 64, 0, stream>>>(
        bn_sum, bn_sumsq, fo_bn2_g, fo_bn2_b, 1.0f / NG, scale, shift);
    head_final_kernel<<<(NG*NC + 255)/256, 256, 0, stream>>>(
        hb, scale, shift, fo3_w, fo3_b, out);
}

// Round 2
// 1672.757 us; speedup vs baseline: 7.4157x; 7.4157x over previous
//
#include <hip/hip_runtime.h>

#define NN 100000
#define NE 1200000
#define DD 64
#define EDIM 16
#define NL 3
#define NG 512
#define NC 10

// ---------------------------------------------------------------------------
// prep: Wc[l] = w_edge @ lin_w[l]   (16x64),  bc[l] = b_edge @ lin_w[l] + lin_b[l]
__global__ __launch_bounds__(1024) void prep_kernel(
    const float* __restrict__ w_edge, const float* __restrict__ b_edge,
    const float* __restrict__ lin_w, const float* __restrict__ lin_b,
    float* __restrict__ Wc, float* __restrict__ bc)
{
    const int l = blockIdx.x;
    const int tid = threadIdx.x;
    const float* Lw = lin_w + l * 4096;
    const int k = tid >> 6, col = tid & 63;
    float acc = 0.f;
    for (int j = 0; j < 64; ++j) acc = fmaf(w_edge[k*64 + j], Lw[j*64 + col], acc);
    Wc[l*1024 + k*64 + col] = acc;
    if (tid < 64) {
        float a = lin_b[l*64 + tid];
        for (int j = 0; j < 64; ++j) a = fmaf(b_edge[j], Lw[j*64 + tid], a);
        bc[l*64 + tid] = a;
    }
}

// ---------------------------------------------------------------------------
// CSR build: histogram of dst
__global__ __launch_bounds__(256) void hist_kernel(
    const int* __restrict__ dst, int* __restrict__ counts)
{
    const int e = blockIdx.x * 256 + threadIdx.x;
    if (e < NE) atomicAdd(&counts[dst[e]], 1);
}

// single-block hierarchical exclusive scan over counts[NN] -> rowptr, next
#define SCAN_CHUNK 98   // 1024 * 98 = 100352 >= NN
__global__ __launch_bounds__(1024) void scan_kernel(
    const int* __restrict__ counts, int* __restrict__ rowptr, int* __restrict__ next)
{
    __shared__ int sPart[1024];
    const int t = threadIdx.x;
    const int base = t * SCAN_CHUNK;
    int s = 0;
    for (int i = 0; i < SCAN_CHUNK; ++i) {
        int idx = base + i;
        if (idx < NN) s += counts[idx];
    }
    sPart[t] = s;
    __syncthreads();
    for (int off = 1; off < 1024; off <<= 1) {
        int v = 0;
        if (t >= off) v = sPart[t - off];
        __syncthreads();
        if (t >= off) sPart[t] += v;
        __syncthreads();
    }
    int run = (t == 0) ? 0 : sPart[t - 1];
    for (int i = 0; i < SCAN_CHUNK; ++i) {
        int idx = base + i;
        if (idx < NN) {
            rowptr[idx] = run;
            next[idx] = run;
            run += counts[idx];
        }
    }
    if (t == 1023) rowptr[NN] = sPart[1023];
}

// scatter edge ids into CSR order
__global__ __launch_bounds__(256) void scatter_kernel(
    const int* __restrict__ dst, int* __restrict__ next, int* __restrict__ csr_eid)
{
    const int e = blockIdx.x * 256 + threadIdx.x;
    if (e >= NE) return;
    const int pos = atomicAdd(&next[dst[e]], 1);
    csr_eid[pos] = e;
}

// ---------------------------------------------------------------------------
// aggregation: one wave per node, lanes = 64 feature columns.
// out[n] = h[n] + sum_{e: dst=n} relu( h[src_e] + edge_attr[e] @ Wc + bc )
__global__ __launch_bounds__(256) void agg_kernel(
    const int* __restrict__ rowptr, const int* __restrict__ csr_eid,
    const int* __restrict__ src_arr, const float* __restrict__ edge_attr,
    const float* __restrict__ Wc, const float* __restrict__ bc,
    const float* __restrict__ h, float* __restrict__ out)
{
    __shared__ __align__(16) float sW[16*64];
    __shared__ __align__(16) float sb[64];
    const int tid = threadIdx.x;
    ((float4*)sW)[tid] = ((const float4*)Wc)[tid];
    if (tid < 16) ((float4*)sb)[tid] = ((const float4*)bc)[tid];
    __syncthreads();

    const int wave = tid >> 6, lane = tid & 63;
    const int n = blockIdx.x * 4 + wave;
    if (n >= NN) return;

    const int start = rowptr[n], end = rowptr[n + 1];
    float acc = h[(size_t)n * 64 + lane];          // fused "+ h" (GINE eps=0)
    const float mb = sb[lane];

    for (int p = start; p < end; ++p) {
        const int eid = csr_eid[p];
        const int s = src_arr[eid];
        const float4* eap = (const float4*)(edge_attr + (size_t)eid * 16);
        float4 e0 = eap[0], e1 = eap[1], e2 = eap[2], e3 = eap[3];
        float m = mb;
        m = fmaf(e0.x, sW[ 0*64 + lane], m);
        m = fmaf(e0.y, sW[ 1*64 + lane], m);
        m = fmaf(e0.z, sW[ 2*64 + lane], m);
        m = fmaf(e0.w, sW[ 3*64 + lane], m);
        m = fmaf(e1.x, sW[ 4*64 + lane], m);
        m = fmaf(e1.y, sW[ 5*64 + lane], m);
        m = fmaf(e1.z, sW[ 6*64 + lane], m);
        m = fmaf(e1.w, sW[ 7*64 + lane], m);
        m = fmaf(e2.x, sW[ 8*64 + lane], m);
        m = fmaf(e2.y, sW[ 9*64 + lane], m);
        m = fmaf(e2.z, sW[10*64 + lane], m);
        m = fmaf(e2.w, sW[11*64 + lane], m);
        m = fmaf(e3.x, sW[12*64 + lane], m);
        m = fmaf(e3.y, sW[13*64 + lane], m);
        m = fmaf(e3.z, sW[14*64 + lane], m);
        m = fmaf(e3.w, sW[15*64 + lane], m);
        const float hv = h[(size_t)s * 64 + lane];
        acc += fmaxf(m + hv, 0.f);
    }
    out[(size_t)n * 64 + lane] = acc;
}

// ---------------------------------------------------------------------------
// Generic [nrows,64] @ [64,64] + bias GEMM.
// IN_MODE: 0 = in0, 2 = relu(in0*scale+shift)
template<int IN_MODE, bool OUT_RELU, bool OUT_ACCUM>
__global__ __launch_bounds__(256) void gemm64_kernel(
    const float* __restrict__ in0,
    const float* __restrict__ W, const float* __restrict__ bias,
    const float* __restrict__ scale, const float* __restrict__ shift,
    float* __restrict__ out, int nrows,
    float* __restrict__ bn_sum, float* __restrict__ bn_sumsq)
{
    __shared__ __align__(16) float sIn[64*64];
    __shared__ float sRed[512];
    const int tid = threadIdx.x;
    const int col = tid & 63;
    const int rq  = tid >> 6;
    const int r0  = blockIdx.x * 64;

    float wreg[64];
    #pragma unroll
    for (int k = 0; k < 64; ++k) wreg[k] = W[k*64 + col];
    const float bcol = bias[col];

    for (int i = tid; i < 1024; i += 256) {
        const int r  = i >> 4;
        const int c4 = (i & 15) * 4;
        const int gr = r0 + r;
        float4 v = make_float4(0.f, 0.f, 0.f, 0.f);
        if (gr < nrows) {
            v = *(const float4*)(in0 + (size_t)gr*64 + c4);
            if constexpr (IN_MODE == 2) {
                float4 s4 = *(const float4*)(scale + c4);
                float4 h4 = *(const float4*)(shift + c4);
                v.x = fmaxf(fmaf(v.x, s4.x, h4.x), 0.f);
                v.y = fmaxf(fmaf(v.y, s4.y, h4.y), 0.f);
                v.z = fmaxf(fmaf(v.z, s4.z, h4.z), 0.f);
                v.w = fmaxf(fmaf(v.w, s4.w, h4.w), 0.f);
            }
        }
        *(float4*)(sIn + r*64 + c4) = v;
    }
    __syncthreads();

    float ps = 0.f, psq = 0.f;
    for (int r = rq; r < 64; r += 4) {
        float acc = bcol;
        #pragma unroll
        for (int k = 0; k < 64; k += 4) {
            float4 a = *(const float4*)(sIn + r*64 + k);
            acc = fmaf(a.x, wreg[k+0], acc);
            acc = fmaf(a.y, wreg[k+1], acc);
            acc = fmaf(a.z, wreg[k+2], acc);
            acc = fmaf(a.w, wreg[k+3], acc);
        }
        const int gr = r0 + r;
        if (gr < nrows) {
            if constexpr (OUT_ACCUM) { ps += acc; psq += acc*acc; }
            out[(size_t)gr*64 + col] = OUT_RELU ? fmaxf(acc, 0.f) : acc;
        }
    }

    if constexpr (OUT_ACCUM) {
        sRed[rq*64 + col]       = ps;
        sRed[256 + rq*64 + col] = psq;
        __syncthreads();
        if (rq == 0) {
            float s = sRed[col] + sRed[64+col] + sRed[128+col] + sRed[192+col];
            float q = sRed[256+col] + sRed[320+col] + sRed[384+col] + sRed[448+col];
            atomicAdd(bn_sum + col, s);
            atomicAdd(bn_sumsq + col, q);
        }
    }
}

// ---------------------------------------------------------------------------
__global__ __launch_bounds__(64) void bn_finalize_kernel(
    const float* __restrict__ sum, const float* __restrict__ sumsq,
    const float* __restrict__ gamma, const float* __restrict__ beta,
    float inv_count, float* __restrict__ scale, float* __restrict__ shift)
{
    const int t = threadIdx.x;
    float mu  = sum[t] * inv_count;
    float var = fmaxf(sumsq[t] * inv_count - mu*mu, 0.f);
    float x = var + 1e-5f;
    float r = rsqrtf(x);
    r = r * (1.5f - 0.5f * x * r * r);
    float sc = gamma[t] * r;
    scale[t] = sc;
    shift[t] = beta[t] - mu * sc;
}

// ---------------------------------------------------------------------------
__global__ __launch_bounds__(64) void pool_kernel(
    const float* __restrict__ h, const int* __restrict__ batch,
    float* __restrict__ pooled)
{
    const int g = blockIdx.x;
    const int lane = threadIdx.x;
    int lo = 0, hi = NN;
    while (lo < hi) { int m = (lo + hi) >> 1; if (batch[m] < g) lo = m + 1; else hi = m; }
    const int start = lo;
    hi = NN;
    while (lo < hi) { int m = (lo + hi) >> 1; if (batch[m] < g + 1) lo = m + 1; else hi = m; }
    const int end = lo;
    float acc = 0.f;
    for (int n = start; n < end; ++n) acc += h[(size_t)n*64 + lane];
    pooled[g*64 + lane] = acc;
}

// ---------------------------------------------------------------------------
__global__ __launch_bounds__(256) void head_final_kernel(
    const float* __restrict__ hb, const float* __restrict__ scale,
    const float* __restrict__ shift, const float* __restrict__ fo3_w,
    const float* __restrict__ fo3_b, float* __restrict__ out)
{
    const int idx = blockIdx.x * 256 + threadIdx.x;
    if (idx >= NG * NC) return;
    const int g = idx / NC, c = idx % NC;
    float acc = fo3_b[c];
    for (int k = 0; k < 64; ++k) {
        float v = fmaf(hb[g*64 + k], scale[k], shift[k]);
        acc = fmaf(v, fo3_w[k*NC + c], acc);
    }
    out[idx] = acc;
}

// ---------------------------------------------------------------------------
extern "C" void kernel_launch(void* const* d_in, const int* in_sizes, int n_in,
                              void* d_out, int out_size, void* d_ws, size_t ws_size,
                              hipStream_t stream) {
    const float* x         = (const float*)d_in[0];
    const int*   edge_index= (const int*)  d_in[1];
    const int*   batch     = (const int*)  d_in[2];
    const float* edge_attr = (const float*)d_in[3];
    const float* w_node    = (const float*)d_in[4];
    const float* b_node    = (const float*)d_in[5];
    const float* w_edge    = (const float*)d_in[6];
    const float* b_edge    = (const float*)d_in[7];
    const float* lin_w     = (const float*)d_in[8];
    const float* lin_b     = (const float*)d_in[9];
    const float* mlp1_w    = (const float*)d_in[10];
    const float* mlp1_b    = (const float*)d_in[11];
    const float* bn1_g     = (const float*)d_in[12];
    const float* bn1_b     = (const float*)d_in[13];
    const float* mlp2_w    = (const float*)d_in[14];
    const float* mlp2_b    = (const float*)d_in[15];
    const float* fo1_w     = (const float*)d_in[16];
    const float* fo1_b     = (const float*)d_in[17];
    const float* fo_bn1_g  = (const float*)d_in[18];
    const float* fo_bn1_b  = (const float*)d_in[19];
    const float* fo2_w     = (const float*)d_in[20];
    const float* fo2_b     = (const float*)d_in[21];
    const float* fo_bn2_g  = (const float*)d_in[22];
    const float* fo_bn2_b  = (const float*)d_in[23];
    const float* fo3_w     = (const float*)d_in[24];
    const float* fo3_b     = (const float*)d_in[25];
    float* out = (float*)d_out;

    char* ws = (char*)d_ws;
    float* h   = (float*)(ws);                     // 25.6 MB
    float* agg = (float*)(ws + 25600000);          // 25.6 MB (CSR-build ints alias here)
    int* counts = (int*)agg;                       // NN ints (dead once layers start)
    int* next   = (int*)agg + NN;                  // NN ints
    int* csr_eid= (int*)(ws + 51200000);           // NE ints (4.8 MB)
    int* rowptr = (int*)(ws + 56000000);           // NN+1 ints
    float* sm   = (float*)(ws + 56500000);
    float* Wc       = sm;            // 3072
    float* bc       = sm + 3072;     // 192
    float* scale    = sm + 3264;     // 64
    float* shift    = sm + 3328;     // 64
    float* bn_sum   = sm + 3392;     // 64
    float* bn_sumsq = sm + 3456;     // 64
    float* pooled   = sm + 3520;     // 32768
    float* ha       = sm + 36288;    // 32768
    float* hb       = sm + 69056;    // 32768

    const int* src = edge_index;
    const int* dst = edge_index + NE;
    float* t = agg;   // alias (safe: per-block read-then-write of own rows)

    const int gemmN_blocks = (NN + 63) / 64;     // 1563
    const int edge_blocks  = (NE + 255) / 256;   // 4688
    const int agg_blocks   = (NN + 3) / 4;       // 25000

    prep_kernel<<<NL, 1024, 0, stream>>>(w_edge, b_edge, lin_w, lin_b, Wc, bc);

    // h = x @ w_node + b_node
    gemm64_kernel<0, false, false><<<gemmN_blocks, 256, 0, stream>>>(
        x, w_node, b_node, nullptr, nullptr, h, NN, nullptr, nullptr);

    // CSR build (per launch; edge_index is an input)
    hipMemsetAsync(counts, 0, NN * sizeof(int), stream);
    hist_kernel<<<edge_blocks, 256, 0, stream>>>(dst, counts);
    scan_kernel<<<1, 1024, 0, stream>>>(counts, rowptr, next);
    scatter_kernel<<<edge_blocks, 256, 0, stream>>>(dst, next, csr_eid);

    for (int l = 0; l < NL; ++l) {
        agg_kernel<<<agg_blocks, 256, 0, stream>>>(
            rowptr, csr_eid, src, edge_attr, Wc + l*1024, bc + l*64, h, agg);
        hipMemsetAsync(bn_sum, 0, 128 * sizeof(float), stream);
        gemm64_kernel<0, false, true><<<gemmN_blocks, 256, 0, stream>>>(
            agg, mlp1_w + l*4096, mlp1_b + l*64, nullptr, nullptr,
            t, NN, bn_sum, bn_sumsq);
        bn_finalize_kernel<<<1, 64, 0, stream>>>(
            bn_sum, bn_sumsq, bn1_g + l*64, bn1_b + l*64, 1.0f / NN, scale, shift);
        gemm64_kernel<2, true, false><<<gemmN_blocks, 256, 0, stream>>>(
            t, mlp2_w + l*4096, mlp2_b + l*64, scale, shift,
            h, NN, nullptr, nullptr);
    }

    pool_kernel<<<NG, 64, 0, stream>>>(h, batch, pooled);

    hipMemsetAsync(bn_sum, 0, 128 * sizeof(float), stream);
    gemm64_kernel<0, false, true><<<NG/64, 256, 0, stream>>>(
        pooled, fo1_w, fo1_b, nullptr, nullptr, ha, NG, bn_sum, bn_sumsq);
    bn_finalize_kernel<<<1, 64, 0, stream>>>(
        bn_sum, bn_sumsq, fo_bn1_g, fo_bn1_b, 1.0f / NG, scale, shift);
    hipMemsetAsync(bn_sum, 0, 128 * sizeof(float), stream);
    gemm64_kernel<2, false, true><<<NG/64, 256, 0, stream>>>(
        ha, fo2_w, fo2_b, scale, shift, hb, NG, bn_sum, bn_sumsq);
    bn_finalize_kernel<<<1, 64, 0, stream>>>(
        bn_sum, bn_sumsq, fo_bn2_g, fo_bn2_b, 1.0f / NG, scale, shift);
    head_final_kernel<<<(NG*NC + 255)/256, 256, 0, stream>>>(
        hb, scale, shift, fo3_w, fo3_b, out);
}

// Round 3
// 1519.266 us; speedup vs baseline: 8.1649x; 1.1010x over previous
//
#include <hip/hip_runtime.h>

#define NN 100000
#define NE 1200000
#define DD 64
#define EDIM 16
#define NL 3
#define NG 512
#define NC 10

// ---------------------------------------------------------------------------
// prep: Wc[l] = w_edge @ lin_w[l]   (16x64),  bc[l] = b_edge @ lin_w[l] + lin_b[l]
__global__ __launch_bounds__(1024) void prep_kernel(
    const float* __restrict__ w_edge, const float* __restrict__ b_edge,
    const float* __restrict__ lin_w, const float* __restrict__ lin_b,
    float* __restrict__ Wc, float* __restrict__ bc)
{
    const int l = blockIdx.x;
    const int tid = threadIdx.x;
    const float* Lw = lin_w + l * 4096;
    const int k = tid >> 6, col = tid & 63;
    float acc = 0.f;
    for (int j = 0; j < 64; ++j) acc = fmaf(w_edge[k*64 + j], Lw[j*64 + col], acc);
    Wc[l*1024 + k*64 + col] = acc;
    if (tid < 64) {
        float a = lin_b[l*64 + tid];
        for (int j = 0; j < 64; ++j) a = fmaf(b_edge[j], Lw[j*64 + tid], a);
        bc[l*64 + tid] = a;
    }
}

// ---------------------------------------------------------------------------
// CSR build: histogram of dst
__global__ __launch_bounds__(256) void hist_kernel(
    const int* __restrict__ dst, int* __restrict__ counts)
{
    const int e = blockIdx.x * 256 + threadIdx.x;
    if (e < NE) atomicAdd(&counts[dst[e]], 1);
}

// single-block hierarchical exclusive scan over counts[NN] -> rowptr, next
#define SCAN_CHUNK 98   // 1024 * 98 = 100352 >= NN
__global__ __launch_bounds__(1024) void scan_kernel(
    const int* __restrict__ counts, int* __restrict__ rowptr, int* __restrict__ next)
{
    __shared__ int sPart[1024];
    const int t = threadIdx.x;
    const int base = t * SCAN_CHUNK;
    int s = 0;
    for (int i = 0; i < SCAN_CHUNK; ++i) {
        int idx = base + i;
        if (idx < NN) s += counts[idx];
    }
    sPart[t] = s;
    __syncthreads();
    for (int off = 1; off < 1024; off <<= 1) {
        int v = 0;
        if (t >= off) v = sPart[t - off];
        __syncthreads();
        if (t >= off) sPart[t] += v;
        __syncthreads();
    }
    int run = (t == 0) ? 0 : sPart[t - 1];
    for (int i = 0; i < SCAN_CHUNK; ++i) {
        int idx = base + i;
        if (idx < NN) {
            rowptr[idx] = run;
            next[idx] = run;
            run += counts[idx];
        }
    }
    if (t == 1023) rowptr[NN] = sPart[1023];
}

// scatter (src, eid) pairs into CSR order
__global__ __launch_bounds__(256) void scatter_kernel(
    const int* __restrict__ src, const int* __restrict__ dst,
    int* __restrict__ next, int2* __restrict__ csr_se)
{
    const int e = blockIdx.x * 256 + threadIdx.x;
    if (e >= NE) return;
    const int pos = atomicAdd(&next[dst[e]], 1);
    csr_se[pos] = make_int2(src[e], e);
}

// ---------------------------------------------------------------------------
// aggregation: one wave per node, lanes = 64 feature columns. No LDS.
// Per-lane Wc column in 16 registers; edge loop unrolled x4 for MLP.
// out[n] = h[n] + sum_{e: dst=n} relu( h[src_e] + edge_attr[e] @ Wc + bc )
__global__ __launch_bounds__(256) void agg_kernel(
    const int* __restrict__ rowptr, const int2* __restrict__ csr_se,
    const float* __restrict__ edge_attr,
    const float* __restrict__ Wc, const float* __restrict__ bc,
    const float* __restrict__ h, float* __restrict__ out)
{
    const int tid = threadIdx.x;
    const int lane = tid & 63;
    const int n = blockIdx.x * 4 + (tid >> 6);
    if (n >= NN) return;

    float wr[16];
    #pragma unroll
    for (int k = 0; k < 16; ++k) wr[k] = Wc[k*64 + lane];
    const float mb = bc[lane];

    const int start = rowptr[n], end = rowptr[n + 1];
    float acc = h[(size_t)n * 64 + lane];          // fused "+ h" (GINE eps=0)

    auto msg = [&](float4 a, float4 b, float4 c, float4 d, float hv) -> float {
        float m = mb;
        m = fmaf(a.x, wr[ 0], m); m = fmaf(a.y, wr[ 1], m);
        m = fmaf(a.z, wr[ 2], m); m = fmaf(a.w, wr[ 3], m);
        m = fmaf(b.x, wr[ 4], m); m = fmaf(b.y, wr[ 5], m);
        m = fmaf(b.z, wr[ 6], m); m = fmaf(b.w, wr[ 7], m);
        m = fmaf(c.x, wr[ 8], m); m = fmaf(c.y, wr[ 9], m);
        m = fmaf(c.z, wr[10], m); m = fmaf(c.w, wr[11], m);
        m = fmaf(d.x, wr[12], m); m = fmaf(d.y, wr[13], m);
        m = fmaf(d.z, wr[14], m); m = fmaf(d.w, wr[15], m);
        return fmaxf(m + hv, 0.f);
    };

    int p = start;
    for (; p + 4 <= end; p += 4) {
        const int2 s0 = csr_se[p+0], s1 = csr_se[p+1];
        const int2 s2 = csr_se[p+2], s3 = csr_se[p+3];
        const float4* q0 = (const float4*)(edge_attr + (size_t)s0.y * 16);
        const float4* q1 = (const float4*)(edge_attr + (size_t)s1.y * 16);
        const float4* q2 = (const float4*)(edge_attr + (size_t)s2.y * 16);
        const float4* q3 = (const float4*)(edge_attr + (size_t)s3.y * 16);
        float4 a0 = q0[0], a1 = q0[1], a2 = q0[2], a3 = q0[3];
        float4 b0 = q1[0], b1 = q1[1], b2 = q1[2], b3 = q1[3];
        float4 c0 = q2[0], c1 = q2[1], c2 = q2[2], c3 = q2[3];
        float4 d0 = q3[0], d1 = q3[1], d2 = q3[2], d3 = q3[3];
        float hv0 = h[(size_t)s0.x * 64 + lane];
        float hv1 = h[(size_t)s1.x * 64 + lane];
        float hv2 = h[(size_t)s2.x * 64 + lane];
        float hv3 = h[(size_t)s3.x * 64 + lane];
        acc += msg(a0, a1, a2, a3, hv0);
        acc += msg(b0, b1, b2, b3, hv1);
        acc += msg(c0, c1, c2, c3, hv2);
        acc += msg(d0, d1, d2, d3, hv3);
    }
    for (; p < end; ++p) {
        const int2 s0 = csr_se[p];
        const float4* q = (const float4*)(edge_attr + (size_t)s0.y * 16);
        float4 a0 = q[0], a1 = q[1], a2 = q[2], a3 = q[3];
        float hv = h[(size_t)s0.x * 64 + lane];
        acc += msg(a0, a1, a2, a3, hv);
    }
    out[(size_t)n * 64 + lane] = acc;
}

// ---------------------------------------------------------------------------
// Generic [nrows,64] @ [64,64] + bias GEMM.
// IN_MODE: 0 = in0, 2 = relu(in0*scale+shift)
template<int IN_MODE, bool OUT_RELU, bool OUT_ACCUM>
__global__ __launch_bounds__(256) void gemm64_kernel(
    const float* __restrict__ in0,
    const float* __restrict__ W, const float* __restrict__ bias,
    const float* __restrict__ scale, const float* __restrict__ shift,
    float* __restrict__ out, int nrows,
    float* __restrict__ bn_sum, float* __restrict__ bn_sumsq)
{
    __shared__ __align__(16) float sIn[64*64];
    __shared__ float sRed[512];
    const int tid = threadIdx.x;
    const int col = tid & 63;
    const int rq  = tid >> 6;
    const int r0  = blockIdx.x * 64;

    float wreg[64];
    #pragma unroll
    for (int k = 0; k < 64; ++k) wreg[k] = W[k*64 + col];
    const float bcol = bias[col];

    for (int i = tid; i < 1024; i += 256) {
        const int r  = i >> 4;
        const int c4 = (i & 15) * 4;
        const int gr = r0 + r;
        float4 v = make_float4(0.f, 0.f, 0.f, 0.f);
        if (gr < nrows) {
            v = *(const float4*)(in0 + (size_t)gr*64 + c4);
            if constexpr (IN_MODE == 2) {
                float4 s4 = *(const float4*)(scale + c4);
                float4 h4 = *(const float4*)(shift + c4);
                v.x = fmaxf(fmaf(v.x, s4.x, h4.x), 0.f);
                v.y = fmaxf(fmaf(v.y, s4.y, h4.y), 0.f);
                v.z = fmaxf(fmaf(v.z, s4.z, h4.z), 0.f);
                v.w = fmaxf(fmaf(v.w, s4.w, h4.w), 0.f);
            }
        }
        *(float4*)(sIn + r*64 + c4) = v;
    }
    __syncthreads();

    float ps = 0.f, psq = 0.f;
    for (int r = rq; r < 64; r += 4) {
        float acc = bcol;
        #pragma unroll
        for (int k = 0; k < 64; k += 4) {
            float4 a = *(const float4*)(sIn + r*64 + k);
            acc = fmaf(a.x, wreg[k+0], acc);
            acc = fmaf(a.y, wreg[k+1], acc);
            acc = fmaf(a.z, wreg[k+2], acc);
            acc = fmaf(a.w, wreg[k+3], acc);
        }
        const int gr = r0 + r;
        if (gr < nrows) {
            if constexpr (OUT_ACCUM) { ps += acc; psq += acc*acc; }
            out[(size_t)gr*64 + col] = OUT_RELU ? fmaxf(acc, 0.f) : acc;
        }
    }

    if constexpr (OUT_ACCUM) {
        sRed[rq*64 + col]       = ps;
        sRed[256 + rq*64 + col] = psq;
        __syncthreads();
        if (rq == 0) {
            float s = sRed[col] + sRed[64+col] + sRed[128+col] + sRed[192+col];
            float q = sRed[256+col] + sRed[320+col] + sRed[384+col] + sRed[448+col];
            atomicAdd(bn_sum + col, s);
            atomicAdd(bn_sumsq + col, q);
        }
    }
}

// ---------------------------------------------------------------------------
__global__ __launch_bounds__(64) void bn_finalize_kernel(
    const float* __restrict__ sum, const float* __restrict__ sumsq,
    const float* __restrict__ gamma, const float* __restrict__ beta,
    float inv_count, float* __restrict__ scale, float* __restrict__ shift)
{
    const int t = threadIdx.x;
    float mu  = sum[t] * inv_count;
    float var = fmaxf(sumsq[t] * inv_count - mu*mu, 0.f);
    float x = var + 1e-5f;
    float r = rsqrtf(x);
    r = r * (1.5f - 0.5f * x * r * r);
    float sc = gamma[t] * r;
    scale[t] = sc;
    shift[t] = beta[t] - mu * sc;
}

// ---------------------------------------------------------------------------
__global__ __launch_bounds__(64) void pool_kernel(
    const float* __restrict__ h, const int* __restrict__ batch,
    float* __restrict__ pooled)
{
    const int g = blockIdx.x;
    const int lane = threadIdx.x;
    int lo = 0, hi = NN;
    while (lo < hi) { int m = (lo + hi) >> 1; if (batch[m] < g) lo = m + 1; else hi = m; }
    const int start = lo;
    hi = NN;
    while (lo < hi) { int m = (lo + hi) >> 1; if (batch[m] < g + 1) lo = m + 1; else hi = m; }
    const int end = lo;
    float acc = 0.f;
    for (int n = start; n < end; ++n) acc += h[(size_t)n*64 + lane];
    pooled[g*64 + lane] = acc;
}

// ---------------------------------------------------------------------------
__global__ __launch_bounds__(256) void head_final_kernel(
    const float* __restrict__ hb, const float* __restrict__ scale,
    const float* __restrict__ shift, const float* __restrict__ fo3_w,
    const float* __restrict__ fo3_b, float* __restrict__ out)
{
    const int idx = blockIdx.x * 256 + threadIdx.x;
    if (idx >= NG * NC) return;
    const int g = idx / NC, c = idx % NC;
    float acc = fo3_b[c];
    for (int k = 0; k < 64; ++k) {
        float v = fmaf(hb[g*64 + k], scale[k], shift[k]);
        acc = fmaf(v, fo3_w[k*NC + c], acc);
    }
    out[idx] = acc;
}

// ---------------------------------------------------------------------------
extern "C" void kernel_launch(void* const* d_in, const int* in_sizes, int n_in,
                              void* d_out, int out_size, void* d_ws, size_t ws_size,
                              hipStream_t stream) {
    const float* x         = (const float*)d_in[0];
    const int*   edge_index= (const int*)  d_in[1];
    const int*   batch     = (const int*)  d_in[2];
    const float* edge_attr = (const float*)d_in[3];
    const float* w_node    = (const float*)d_in[4];
    const float* b_node    = (const float*)d_in[5];
    const float* w_edge    = (const float*)d_in[6];
    const float* b_edge    = (const float*)d_in[7];
    const float* lin_w     = (const float*)d_in[8];
    const float* lin_b     = (const float*)d_in[9];
    const float* mlp1_w    = (const float*)d_in[10];
    const float* mlp1_b    = (const float*)d_in[11];
    const float* bn1_g     = (const float*)d_in[12];
    const float* bn1_b     = (const float*)d_in[13];
    const float* mlp2_w    = (const float*)d_in[14];
    const float* mlp2_b    = (const float*)d_in[15];
    const float* fo1_w     = (const float*)d_in[16];
    const float* fo1_b     = (const float*)d_in[17];
    const float* fo_bn1_g  = (const float*)d_in[18];
    const float* fo_bn1_b  = (const float*)d_in[19];
    const float* fo2_w     = (const float*)d_in[20];
    const float* fo2_b     = (const float*)d_in[21];
    const float* fo_bn2_g  = (const float*)d_in[22];
    const float* fo_bn2_b  = (const float*)d_in[23];
    const float* fo3_w     = (const float*)d_in[24];
    const float* fo3_b     = (const float*)d_in[25];
    float* out = (float*)d_out;

    char* ws = (char*)d_ws;
    float* h   = (float*)(ws);                     // 25.6 MB
    float* agg = (float*)(ws + 25600000);          // 25.6 MB (CSR-build ints alias here)
    int* counts = (int*)agg;                       // NN ints (dead once layers start)
    int* next   = (int*)agg + NN;                  // NN ints
    int2* csr_se= (int2*)(ws + 51200000);          // NE int2 (9.6 MB)
    int* rowptr = (int*)(ws + 60800000);           // NN+1 ints
    float* sm   = (float*)(ws + 61300000);
    float* Wc       = sm;            // 3072
    float* bc       = sm + 3072;     // 192
    float* scale    = sm + 3264;     // 64
    float* shift    = sm + 3328;     // 64
    float* bn_sum   = sm + 3392;     // 64
    float* bn_sumsq = sm + 3456;     // 64
    float* pooled   = sm + 3520;     // 32768
    float* ha       = sm + 36288;    // 32768
    float* hb       = sm + 69056;    // 32768

    const int* src = edge_index;
    const int* dst = edge_index + NE;
    float* t = agg;   // alias (safe: per-block read-then-write of own rows)

    const int gemmN_blocks = (NN + 63) / 64;     // 1563
    const int edge_blocks  = (NE + 255) / 256;   // 4688
    const int agg_blocks   = (NN + 3) / 4;       // 25000

    prep_kernel<<<NL, 1024, 0, stream>>>(w_edge, b_edge, lin_w, lin_b, Wc, bc);

    // h = x @ w_node + b_node
    gemm64_kernel<0, false, false><<<gemmN_blocks, 256, 0, stream>>>(
        x, w_node, b_node, nullptr, nullptr, h, NN, nullptr, nullptr);

    // CSR build (per launch; edge_index is an input)
    hipMemsetAsync(counts, 0, NN * sizeof(int), stream);
    hist_kernel<<<edge_blocks, 256, 0, stream>>>(dst, counts);
    scan_kernel<<<1, 1024, 0, stream>>>(counts, rowptr, next);
    scatter_kernel<<<edge_blocks, 256, 0, stream>>>(src, dst, next, csr_se);

    for (int l = 0; l < NL; ++l) {
        agg_kernel<<<agg_blocks, 256, 0, stream>>>(
            rowptr, csr_se, edge_attr, Wc + l*1024, bc + l*64, h, agg);
        hipMemsetAsync(bn_sum, 0, 128 * sizeof(float), stream);
        gemm64_kernel<0, false, true><<<gemmN_blocks, 256, 0, stream>>>(
            agg, mlp1_w + l*4096, mlp1_b + l*64, nullptr, nullptr,
            t, NN, bn_sum, bn_sumsq);
        bn_finalize_kernel<<<1, 64, 0, stream>>>(
            bn_sum, bn_sumsq, bn1_g + l*64, bn1_b + l*64, 1.0f / NN, scale, shift);
        gemm64_kernel<2, true, false><<<gemmN_blocks, 256, 0, stream>>>(
            t, mlp2_w + l*4096, mlp2_b + l*64, scale, shift,
            h, NN, nullptr, nullptr);
    }

    pool_kernel<<<NG, 64, 0, stream>>>(h, batch, pooled);

    hipMemsetAsync(bn_sum, 0, 128 * sizeof(float), stream);
    gemm64_kernel<0, false, true><<<NG/64, 256, 0, stream>>>(
        pooled, fo1_w, fo1_b, nullptr, nullptr, ha, NG, bn_sum, bn_sumsq);
    bn_finalize_kernel<<<1, 64, 0, stream>>>(
        bn_sum, bn_sumsq, fo_bn1_g, fo_bn1_b, 1.0f / NG, scale, shift);
    hipMemsetAsync(bn_sum, 0, 128 * sizeof(float), stream);
    gemm64_kernel<2, false, true><<<NG/64, 256, 0, stream>>>(
        ha, fo2_w, fo2_b, scale, shift, hb, NG, bn_sum, bn_sumsq);
    bn_finalize_kernel<<<1, 64, 0, stream>>>(
        bn_sum, bn_sumsq, fo_bn2_g, fo_bn2_b, 1.0f / NG, scale, shift);
    head_final_kernel<<<(NG*NC + 255)/256, 256, 0, stream>>>(
        hb, scale, shift, fo3_w, fo3_b, out);
}

// Round 4
// 1291.394 us; speedup vs baseline: 9.6056x; 1.1765x over previous
//
#include <hip/hip_runtime.h>

#define NN 100000
#define NE 1200000
#define DD 64
#define EDIM 16
#define NL 3
#define NG 512
#define NC 10
#define NB_SCAN ((NN + 255) / 256)   // 391

// ---------------------------------------------------------------------------
// prep: Wc[l] = w_edge @ lin_w[l]   (16x64),  bc[l] = b_edge @ lin_w[l] + lin_b[l]
__global__ __launch_bounds__(1024) void prep_kernel(
    const float* __restrict__ w_edge, const float* __restrict__ b_edge,
    const float* __restrict__ lin_w, const float* __restrict__ lin_b,
    float* __restrict__ Wc, float* __restrict__ bc)
{
    const int l = blockIdx.x;
    const int tid = threadIdx.x;
    const float* Lw = lin_w + l * 4096;
    const int k = tid >> 6, col = tid & 63;
    float acc = 0.f;
    for (int j = 0; j < 64; ++j) acc = fmaf(w_edge[k*64 + j], Lw[j*64 + col], acc);
    Wc[l*1024 + k*64 + col] = acc;
    if (tid < 64) {
        float a = lin_b[l*64 + tid];
        for (int j = 0; j < 64; ++j) a = fmaf(b_edge[j], Lw[j*64 + tid], a);
        bc[l*64 + tid] = a;
    }
}

// ---------------------------------------------------------------------------
// CSR build: histogram of dst
__global__ __launch_bounds__(256) void hist_kernel(
    const int* __restrict__ dst, int* __restrict__ counts)
{
    const int e = blockIdx.x * 256 + threadIdx.x;
    if (e < NE) atomicAdd(&counts[dst[e]], 1);
}

// ---- multi-block exclusive scan over counts[NN] (3 phases) ----------------
__global__ __launch_bounds__(256) void scan_reduce_kernel(
    const int* __restrict__ counts, int* __restrict__ bsum)
{
    __shared__ int sd[256];
    const int t = threadIdx.x;
    const int idx = blockIdx.x * 256 + t;
    sd[t] = (idx < NN) ? counts[idx] : 0;
    __syncthreads();
    for (int off = 128; off > 0; off >>= 1) {
        if (t < off) sd[t] += sd[t + off];
        __syncthreads();
    }
    if (t == 0) bsum[blockIdx.x] = sd[0];
}

__global__ __launch_bounds__(512) void scan_partials_kernel(
    const int* __restrict__ bsum, int* __restrict__ bscan)
{
    __shared__ int sd[512];
    const int t = threadIdx.x;
    sd[t] = (t < NB_SCAN) ? bsum[t] : 0;
    __syncthreads();
    for (int off = 1; off < 512; off <<= 1) {
        int u = (t >= off) ? sd[t - off] : 0;
        __syncthreads();
        sd[t] += u;
        __syncthreads();
    }
    if (t < NB_SCAN) bscan[t] = (t == 0) ? 0 : sd[t - 1];
}

__global__ __launch_bounds__(256) void scan_final_kernel(
    const int* __restrict__ counts, const int* __restrict__ bscan,
    int* __restrict__ rowptr, int* __restrict__ next)
{
    __shared__ int sd[256];
    const int t = threadIdx.x;
    const int idx = blockIdx.x * 256 + t;
    const int v = (idx < NN) ? counts[idx] : 0;
    sd[t] = v;
    __syncthreads();
    for (int off = 1; off < 256; off <<= 1) {
        int u = (t >= off) ? sd[t - off] : 0;
        __syncthreads();
        sd[t] += u;
        __syncthreads();
    }
    const int excl = sd[t] - v + bscan[blockIdx.x];
    if (idx < NN) { rowptr[idx] = excl; next[idx] = excl; }
    if (idx == NN - 1) rowptr[NN] = excl + v;
}

// scatter (src, eid) pairs into CSR order
__global__ __launch_bounds__(256) void scatter_kernel(
    const int* __restrict__ src, const int* __restrict__ dst,
    int* __restrict__ next, int2* __restrict__ csr_se)
{
    const int e = blockIdx.x * 256 + threadIdx.x;
    if (e >= NE) return;
    const int pos = atomicAdd(&next[dst[e]], 1);
    csr_se[pos] = make_int2(src[e], e);
}

// ---------------------------------------------------------------------------
// aggregation: one wave per node, lanes = 64 feature columns. No LDS.
__global__ __launch_bounds__(256) void agg_kernel(
    const int* __restrict__ rowptr, const int2* __restrict__ csr_se,
    const float* __restrict__ edge_attr,
    const float* __restrict__ Wc, const float* __restrict__ bc,
    const float* __restrict__ h, float* __restrict__ out)
{
    const int tid = threadIdx.x;
    const int lane = tid & 63;
    const int n = blockIdx.x * 4 + (tid >> 6);
    if (n >= NN) return;

    float wr[16];
    #pragma unroll
    for (int k = 0; k < 16; ++k) wr[k] = Wc[k*64 + lane];
    const float mb = bc[lane];

    const int start = rowptr[n], end = rowptr[n + 1];
    float acc = h[(size_t)n * 64 + lane];          // fused "+ h" (GINE eps=0)

    auto msg = [&](float4 a, float4 b, float4 c, float4 d, float hv) -> float {
        float m = mb;
        m = fmaf(a.x, wr[ 0], m); m = fmaf(a.y, wr[ 1], m);
        m = fmaf(a.z, wr[ 2], m); m = fmaf(a.w, wr[ 3], m);
        m = fmaf(b.x, wr[ 4], m); m = fmaf(b.y, wr[ 5], m);
        m = fmaf(b.z, wr[ 6], m); m = fmaf(b.w, wr[ 7], m);
        m = fmaf(c.x, wr[ 8], m); m = fmaf(c.y, wr[ 9], m);
        m = fmaf(c.z, wr[10], m); m = fmaf(c.w, wr[11], m);
        m = fmaf(d.x, wr[12], m); m = fmaf(d.y, wr[13], m);
        m = fmaf(d.z, wr[14], m); m = fmaf(d.w, wr[15], m);
        return fmaxf(m + hv, 0.f);
    };

    int p = start;
    for (; p + 4 <= end; p += 4) {
        const int2 s0 = csr_se[p+0], s1 = csr_se[p+1];
        const int2 s2 = csr_se[p+2], s3 = csr_se[p+3];
        const float4* q0 = (const float4*)(edge_attr + (size_t)s0.y * 16);
        const float4* q1 = (const float4*)(edge_attr + (size_t)s1.y * 16);
        const float4* q2 = (const float4*)(edge_attr + (size_t)s2.y * 16);
        const float4* q3 = (const float4*)(edge_attr + (size_t)s3.y * 16);
        float4 a0 = q0[0], a1 = q0[1], a2 = q0[2], a3 = q0[3];
        float4 b0 = q1[0], b1 = q1[1], b2 = q1[2], b3 = q1[3];
        float4 c0 = q2[0], c1 = q2[1], c2 = q2[2], c3 = q2[3];
        float4 d0 = q3[0], d1 = q3[1], d2 = q3[2], d3 = q3[3];
        float hv0 = h[(size_t)s0.x * 64 + lane];
        float hv1 = h[(size_t)s1.x * 64 + lane];
        float hv2 = h[(size_t)s2.x * 64 + lane];
        float hv3 = h[(size_t)s3.x * 64 + lane];
        acc += msg(a0, a1, a2, a3, hv0);
        acc += msg(b0, b1, b2, b3, hv1);
        acc += msg(c0, c1, c2, c3, hv2);
        acc += msg(d0, d1, d2, d3, hv3);
    }
    for (; p < end; ++p) {
        const int2 s0 = csr_se[p];
        const float4* q = (const float4*)(edge_attr + (size_t)s0.y * 16);
        float4 a0 = q[0], a1 = q[1], a2 = q[2], a3 = q[3];
        float hv = h[(size_t)s0.x * 64 + lane];
        acc += msg(a0, a1, a2, a3, hv);
    }
    out[(size_t)n * 64 + lane] = acc;
}

// ---------------------------------------------------------------------------
// [nrows,64] @ [64,64] + bias GEMM, 2-col register tiling.
// Each thread: cols {c, c+32}, 8 rows (r = rg + 8*i) -> each ds_read_b128
// feeds 8 FMAs instead of 4.
// IN_MODE: 0 = in0, 2 = relu(in0*scale+shift)
template<int IN_MODE, bool OUT_RELU, bool OUT_ACCUM>
__global__ __launch_bounds__(256) void gemm64_kernel(
    const float* __restrict__ in0,
    const float* __restrict__ W, const float* __restrict__ bias,
    const float* __restrict__ scale, const float* __restrict__ shift,
    float* __restrict__ out, int nrows,
    float* __restrict__ bn_sum, float* __restrict__ bn_sumsq)
{
    __shared__ __align__(16) float sIn[64*64];
    __shared__ float sRedS[512];
    __shared__ float sRedQ[512];
    const int tid = threadIdx.x;
    const int c  = tid & 31;      // columns c and c+32
    const int rg = tid >> 5;      // 8 row-groups
    const int r0 = blockIdx.x * 64;

    float w0[64], w1[64];
    #pragma unroll
    for (int k = 0; k < 64; ++k) { w0[k] = W[k*64 + c]; w1[k] = W[k*64 + c + 32]; }
    const float b0 = bias[c], b1 = bias[c + 32];

    for (int i = tid; i < 1024; i += 256) {
        const int r  = i >> 4;
        const int c4 = (i & 15) * 4;
        const int gr = r0 + r;
        float4 v = make_float4(0.f, 0.f, 0.f, 0.f);
        if (gr < nrows) {
            v = *(const float4*)(in0 + (size_t)gr*64 + c4);
            if constexpr (IN_MODE == 2) {
                float4 s4 = *(const float4*)(scale + c4);
                float4 h4 = *(const float4*)(shift + c4);
                v.x = fmaxf(fmaf(v.x, s4.x, h4.x), 0.f);
                v.y = fmaxf(fmaf(v.y, s4.y, h4.y), 0.f);
                v.z = fmaxf(fmaf(v.z, s4.z, h4.z), 0.f);
                v.w = fmaxf(fmaf(v.w, s4.w, h4.w), 0.f);
            }
        }
        *(float4*)(sIn + r*64 + c4) = v;
    }
    __syncthreads();

    float ps0 = 0.f, psq0 = 0.f, ps1 = 0.f, psq1 = 0.f;
    #pragma unroll
    for (int i = 0; i < 8; ++i) {
        const int r = rg + 8*i;
        float a0 = b0, a1 = b1;
        #pragma unroll
        for (int k = 0; k < 64; k += 4) {
            float4 a = *(const float4*)(sIn + r*64 + k);
            a0 = fmaf(a.x, w0[k+0], a0); a1 = fmaf(a.x, w1[k+0], a1);
            a0 = fmaf(a.y, w0[k+1], a0); a1 = fmaf(a.y, w1[k+1], a1);
            a0 = fmaf(a.z, w0[k+2], a0); a1 = fmaf(a.z, w1[k+2], a1);
            a0 = fmaf(a.w, w0[k+3], a0); a1 = fmaf(a.w, w1[k+3], a1);
        }
        const int gr = r0 + r;
        if (gr < nrows) {
            if constexpr (OUT_ACCUM) {
                ps0 += a0; psq0 += a0*a0;
                ps1 += a1; psq1 += a1*a1;
            }
            out[(size_t)gr*64 + c]      = OUT_RELU ? fmaxf(a0, 0.f) : a0;
            out[(size_t)gr*64 + c + 32] = OUT_RELU ? fmaxf(a1, 0.f) : a1;
        }
    }

    if constexpr (OUT_ACCUM) {
        sRedS[rg*64 + c]      = ps0;
        sRedS[rg*64 + c + 32] = ps1;
        sRedQ[rg*64 + c]      = psq0;
        sRedQ[rg*64 + c + 32] = psq1;
        __syncthreads();
        if (tid < 64) {
            float s = 0.f, q = 0.f;
            #pragma unroll
            for (int g = 0; g < 8; ++g) { s += sRedS[g*64 + tid]; q += sRedQ[g*64 + tid]; }
            atomicAdd(bn_sum + tid, s);
            atomicAdd(bn_sumsq + tid, q);
        }
    }
}

// ---------------------------------------------------------------------------
__global__ __launch_bounds__(64) void bn_finalize_kernel(
    const float* __restrict__ sum, const float* __restrict__ sumsq,
    const float* __restrict__ gamma, const float* __restrict__ beta,
    float inv_count, float* __restrict__ scale, float* __restrict__ shift)
{
    const int t = threadIdx.x;
    float mu  = sum[t] * inv_count;
    float var = fmaxf(sumsq[t] * inv_count - mu*mu, 0.f);
    float x = var + 1e-5f;
    float r = rsqrtf(x);
    r = r * (1.5f - 0.5f * x * r * r);
    float sc = gamma[t] * r;
    scale[t] = sc;
    shift[t] = beta[t] - mu * sc;
}

// ---------------------------------------------------------------------------
__global__ __launch_bounds__(64) void pool_kernel(
    const float* __restrict__ h, const int* __restrict__ batch,
    float* __restrict__ pooled)
{
    const int g = blockIdx.x;
    const int lane = threadIdx.x;
    int lo = 0, hi = NN;
    while (lo < hi) { int m = (lo + hi) >> 1; if (batch[m] < g) lo = m + 1; else hi = m; }
    const int start = lo;
    hi = NN;
    while (lo < hi) { int m = (lo + hi) >> 1; if (batch[m] < g + 1) lo = m + 1; else hi = m; }
    const int end = lo;
    float acc = 0.f;
    for (int n = start; n < end; ++n) acc += h[(size_t)n*64 + lane];
    pooled[g*64 + lane] = acc;
}

// ---------------------------------------------------------------------------
__global__ __launch_bounds__(256) void head_final_kernel(
    const float* __restrict__ hb, const float* __restrict__ scale,
    const float* __restrict__ shift, const float* __restrict__ fo3_w,
    const float* __restrict__ fo3_b, float* __restrict__ out)
{
    const int idx = blockIdx.x * 256 + threadIdx.x;
    if (idx >= NG * NC) return;
    const int g = idx / NC, c = idx % NC;
    float acc = fo3_b[c];
    for (int k = 0; k < 64; ++k) {
        float v = fmaf(hb[g*64 + k], scale[k], shift[k]);
        acc = fmaf(v, fo3_w[k*NC + c], acc);
    }
    out[idx] = acc;
}

// ---------------------------------------------------------------------------
extern "C" void kernel_launch(void* const* d_in, const int* in_sizes, int n_in,
                              void* d_out, int out_size, void* d_ws, size_t ws_size,
                              hipStream_t stream) {
    const float* x         = (const float*)d_in[0];
    const int*   edge_index= (const int*)  d_in[1];
    const int*   batch     = (const int*)  d_in[2];
    const float* edge_attr = (const float*)d_in[3];
    const float* w_node    = (const float*)d_in[4];
    const float* b_node    = (const float*)d_in[5];
    const float* w_edge    = (const float*)d_in[6];
    const float* b_edge    = (const float*)d_in[7];
    const float* lin_w     = (const float*)d_in[8];
    const float* lin_b     = (const float*)d_in[9];
    const float* mlp1_w    = (const float*)d_in[10];
    const float* mlp1_b    = (const float*)d_in[11];
    const float* bn1_g     = (const float*)d_in[12];
    const float* bn1_b     = (const float*)d_in[13];
    const float* mlp2_w    = (const float*)d_in[14];
    const float* mlp2_b    = (const float*)d_in[15];
    const float* fo1_w     = (const float*)d_in[16];
    const float* fo1_b     = (const float*)d_in[17];
    const float* fo_bn1_g  = (const float*)d_in[18];
    const float* fo_bn1_b  = (const float*)d_in[19];
    const float* fo2_w     = (const float*)d_in[20];
    const float* fo2_b     = (const float*)d_in[21];
    const float* fo_bn2_g  = (const float*)d_in[22];
    const float* fo_bn2_b  = (const float*)d_in[23];
    const float* fo3_w     = (const float*)d_in[24];
    const float* fo3_b     = (const float*)d_in[25];
    float* out = (float*)d_out;

    char* ws = (char*)d_ws;
    float* h   = (float*)(ws);                     // 25.6 MB
    float* agg = (float*)(ws + 25600000);          // 25.6 MB (CSR-build ints alias here)
    int* counts = (int*)agg;                       // NN ints (dead once layers start)
    int* next   = (int*)agg + NN;                  // NN ints
    int2* csr_se= (int2*)(ws + 51200000);          // NE int2 (9.6 MB)
    int* rowptr = (int*)(ws + 60800000);           // NN+1 ints
    float* sm   = (float*)(ws + 61300000);
    float* Wc       = sm;            // 3072
    float* bc       = sm + 3072;     // 192
    float* scale    = sm + 3264;     // 64
    float* shift    = sm + 3328;     // 64
    float* bn_sum   = sm + 3392;     // 64
    float* bn_sumsq = sm + 3456;     // 64
    float* pooled   = sm + 3520;     // 32768
    float* ha       = sm + 36288;    // 32768
    float* hb       = sm + 69056;    // 32768
    int* bsum       = (int*)(sm + 102000);   // NB_SCAN ints
    int* bscan      = bsum + 512;            // NB_SCAN ints

    const int* src = edge_index;
    const int* dst = edge_index + NE;
    float* t = agg;   // alias (safe: per-block read-then-write of own rows)

    const int gemmN_blocks = (NN + 63) / 64;     // 1563
    const int edge_blocks  = (NE + 255) / 256;   // 4688
    const int agg_blocks   = (NN + 3) / 4;       // 25000

    prep_kernel<<<NL, 1024, 0, stream>>>(w_edge, b_edge, lin_w, lin_b, Wc, bc);

    // h = x @ w_node + b_node
    gemm64_kernel<0, false, false><<<gemmN_blocks, 256, 0, stream>>>(
        x, w_node, b_node, nullptr, nullptr, h, NN, nullptr, nullptr);

    // CSR build (per launch; edge_index is an input)
    hipMemsetAsync(counts, 0, NN * sizeof(int), stream);
    hist_kernel<<<edge_blocks, 256, 0, stream>>>(dst, counts);
    scan_reduce_kernel<<<NB_SCAN, 256, 0, stream>>>(counts, bsum);
    scan_partials_kernel<<<1, 512, 0, stream>>>(bsum, bscan);
    scan_final_kernel<<<NB_SCAN, 256, 0, stream>>>(counts, bscan, rowptr, next);
    scatter_kernel<<<edge_blocks, 256, 0, stream>>>(src, dst, next, csr_se);

    for (int l = 0; l < NL; ++l) {
        agg_kernel<<<agg_blocks, 256, 0, stream>>>(
            rowptr, csr_se, edge_attr, Wc + l*1024, bc + l*64, h, agg);
        hipMemsetAsync(bn_sum, 0, 128 * sizeof(float), stream);
        gemm64_kernel<0, false, true><<<gemmN_blocks, 256, 0, stream>>>(
            agg, mlp1_w + l*4096, mlp1_b + l*64, nullptr, nullptr,
            t, NN, bn_sum, bn_sumsq);
        bn_finalize_kernel<<<1, 64, 0, stream>>>(
            bn_sum, bn_sumsq, bn1_g + l*64, bn1_b + l*64, 1.0f / NN, scale, shift);
        gemm64_kernel<2, true, false><<<gemmN_blocks, 256, 0, stream>>>(
            t, mlp2_w + l*4096, mlp2_b + l*64, scale, shift,
            h, NN, nullptr, nullptr);
    }

    pool_kernel<<<NG, 64, 0, stream>>>(h, batch, pooled);

    hipMemsetAsync(bn_sum, 0, 128 * sizeof(float), stream);
    gemm64_kernel<0, false, true><<<NG/64, 256, 0, stream>>>(
        pooled, fo1_w, fo1_b, nullptr, nullptr, ha, NG, bn_sum, bn_sumsq);
    bn_finalize_kernel<<<1, 64, 0, stream>>>(
        bn_sum, bn_sumsq, fo_bn1_g, fo_bn1_b, 1.0f / NG, scale, shift);
    hipMemsetAsync(bn_sum, 0, 128 * sizeof(float), stream);
    gemm64_kernel<2, false, true><<<NG/64, 256, 0, stream>>>(
        ha, fo2_w, fo2_b, scale, shift, hb, NG, bn_sum, bn_sumsq);
    bn_finalize_kernel<<<1, 64, 0, stream>>>(
        bn_sum, bn_sumsq, fo_bn2_g, fo_bn2_b, 1.0f / NG, scale, shift);
    head_final_kernel<<<(NG*NC + 255)/256, 256, 0, stream>>>(
        hb, scale, shift, fo3_w, fo3_b, out);
}

// Round 5
// 1052.603 us; speedup vs baseline: 11.7847x; 1.2269x over previous
//
#include <hip/hip_runtime.h>

#define NN 100000
#define NE 1200000
#define DD 64
#define EDIM 16
#define NL 3
#define NG 512
#define NC 10
#define NB_SCAN ((NN + 255) / 256)   // 391

__device__ __forceinline__ unsigned pack_bf16(float a, float b) {
    unsigned ua = __float_as_uint(a), ub = __float_as_uint(b);
    ua = (ua + 0x7fffu + ((ua >> 16) & 1u)) >> 16;
    ub = (ub + 0x7fffu + ((ub >> 16) & 1u)) >> 16;
    return ua | (ub << 16);
}
__device__ __forceinline__ float bf_lo(unsigned u) { return __uint_as_float(u << 16); }
__device__ __forceinline__ float bf_hi(unsigned u) { return __uint_as_float(u & 0xffff0000u); }

// ---------------------------------------------------------------------------
// prep: Wc[l] = w_edge @ lin_w[l]   (16x64),  bc[l] = b_edge @ lin_w[l] + lin_b[l]
__global__ __launch_bounds__(1024) void prep_kernel(
    const float* __restrict__ w_edge, const float* __restrict__ b_edge,
    const float* __restrict__ lin_w, const float* __restrict__ lin_b,
    float* __restrict__ Wc, float* __restrict__ bc)
{
    const int l = blockIdx.x;
    const int tid = threadIdx.x;
    const float* Lw = lin_w + l * 4096;
    const int k = tid >> 6, col = tid & 63;
    float acc = 0.f;
    for (int j = 0; j < 64; ++j) acc = fmaf(w_edge[k*64 + j], Lw[j*64 + col], acc);
    Wc[l*1024 + k*64 + col] = acc;
    if (tid < 64) {
        float a = lin_b[l*64 + tid];
        for (int j = 0; j < 64; ++j) a = fmaf(b_edge[j], Lw[j*64 + tid], a);
        bc[l*64 + tid] = a;
    }
}

// ---------------------------------------------------------------------------
// CSR build: histogram of dst
__global__ __launch_bounds__(256) void hist_kernel(
    const int* __restrict__ dst, int* __restrict__ counts)
{
    const int e = blockIdx.x * 256 + threadIdx.x;
    if (e < NE) atomicAdd(&counts[dst[e]], 1);
}

// ---- multi-block exclusive scan over counts[NN] (3 phases) ----------------
__global__ __launch_bounds__(256) void scan_reduce_kernel(
    const int* __restrict__ counts, int* __restrict__ bsum)
{
    __shared__ int sd[256];
    const int t = threadIdx.x;
    const int idx = blockIdx.x * 256 + t;
    sd[t] = (idx < NN) ? counts[idx] : 0;
    __syncthreads();
    for (int off = 128; off > 0; off >>= 1) {
        if (t < off) sd[t] += sd[t + off];
        __syncthreads();
    }
    if (t == 0) bsum[blockIdx.x] = sd[0];
}

__global__ __launch_bounds__(512) void scan_partials_kernel(
    const int* __restrict__ bsum, int* __restrict__ bscan)
{
    __shared__ int sd[512];
    const int t = threadIdx.x;
    sd[t] = (t < NB_SCAN) ? bsum[t] : 0;
    __syncthreads();
    for (int off = 1; off < 512; off <<= 1) {
        int u = (t >= off) ? sd[t - off] : 0;
        __syncthreads();
        sd[t] += u;
        __syncthreads();
    }
    if (t < NB_SCAN) bscan[t] = (t == 0) ? 0 : sd[t - 1];
}

__global__ __launch_bounds__(256) void scan_final_kernel(
    const int* __restrict__ counts, const int* __restrict__ bscan,
    int* __restrict__ rowptr, int* __restrict__ next)
{
    __shared__ int sd[256];
    const int t = threadIdx.x;
    const int idx = blockIdx.x * 256 + t;
    const int v = (idx < NN) ? counts[idx] : 0;
    sd[t] = v;
    __syncthreads();
    for (int off = 1; off < 256; off <<= 1) {
        int u = (t >= off) ? sd[t - off] : 0;
        __syncthreads();
        sd[t] += u;
        __syncthreads();
    }
    const int excl = sd[t] - v + bscan[blockIdx.x];
    if (idx < NN) { rowptr[idx] = excl; next[idx] = excl; }
    if (idx == NN - 1) rowptr[NN] = excl + v;
}

// scatter: src index + bf16-packed edge_attr row into CSR order
__global__ __launch_bounds__(256) void scatter_kernel(
    const int* __restrict__ src, const int* __restrict__ dst,
    const float* __restrict__ edge_attr,
    int* __restrict__ next, int* __restrict__ csr_src, uint4* __restrict__ csr_ea)
{
    const int e = blockIdx.x * 256 + threadIdx.x;
    if (e >= NE) return;
    const float4* q = (const float4*)(edge_attr + (size_t)e * 16);
    float4 a0 = q[0], a1 = q[1], a2 = q[2], a3 = q[3];
    const int pos = atomicAdd(&next[dst[e]], 1);
    csr_src[pos] = src[e];
    uint4 A, B;
    A.x = pack_bf16(a0.x, a0.y); A.y = pack_bf16(a0.z, a0.w);
    A.z = pack_bf16(a1.x, a1.y); A.w = pack_bf16(a1.z, a1.w);
    B.x = pack_bf16(a2.x, a2.y); B.y = pack_bf16(a2.z, a2.w);
    B.z = pack_bf16(a3.x, a3.y); B.w = pack_bf16(a3.z, a3.w);
    csr_ea[(size_t)pos*2 + 0] = A;
    csr_ea[(size_t)pos*2 + 1] = B;
}

// ---------------------------------------------------------------------------
// aggregation: one wave per node, lanes = 64 feature columns. No LDS.
// Edge stream (csr_src, csr_ea) is sequential & wave-uniform; only h[src]
// is a random gather.
__global__ __launch_bounds__(256) void agg_kernel(
    const int* __restrict__ rowptr, const int* __restrict__ csr_src,
    const uint4* __restrict__ csr_ea,
    const float* __restrict__ Wc, const float* __restrict__ bc,
    const float* __restrict__ h, float* __restrict__ out)
{
    const int tid = threadIdx.x;
    const int lane = tid & 63;
    const int n = blockIdx.x * 4 + (tid >> 6);
    if (n >= NN) return;

    float wr[16];
    #pragma unroll
    for (int k = 0; k < 16; ++k) wr[k] = Wc[k*64 + lane];
    const float mb = bc[lane];

    const int start = rowptr[n], end = rowptr[n + 1];
    float acc = h[(size_t)n * 64 + lane];          // fused "+ h" (GINE eps=0)

    auto msg = [&](uint4 A, uint4 B, float hv) -> float {
        float m = mb;
        m = fmaf(bf_lo(A.x), wr[ 0], m); m = fmaf(bf_hi(A.x), wr[ 1], m);
        m = fmaf(bf_lo(A.y), wr[ 2], m); m = fmaf(bf_hi(A.y), wr[ 3], m);
        m = fmaf(bf_lo(A.z), wr[ 4], m); m = fmaf(bf_hi(A.z), wr[ 5], m);
        m = fmaf(bf_lo(A.w), wr[ 6], m); m = fmaf(bf_hi(A.w), wr[ 7], m);
        m = fmaf(bf_lo(B.x), wr[ 8], m); m = fmaf(bf_hi(B.x), wr[ 9], m);
        m = fmaf(bf_lo(B.y), wr[10], m); m = fmaf(bf_hi(B.y), wr[11], m);
        m = fmaf(bf_lo(B.z), wr[12], m); m = fmaf(bf_hi(B.z), wr[13], m);
        m = fmaf(bf_lo(B.w), wr[14], m); m = fmaf(bf_hi(B.w), wr[15], m);
        return fmaxf(m + hv, 0.f);
    };

    int p = start;
    for (; p + 4 <= end; p += 4) {
        const int s0 = csr_src[p+0], s1 = csr_src[p+1];
        const int s2 = csr_src[p+2], s3 = csr_src[p+3];
        uint4 A0 = csr_ea[(size_t)(p+0)*2], B0 = csr_ea[(size_t)(p+0)*2 + 1];
        uint4 A1 = csr_ea[(size_t)(p+1)*2], B1 = csr_ea[(size_t)(p+1)*2 + 1];
        uint4 A2 = csr_ea[(size_t)(p+2)*2], B2 = csr_ea[(size_t)(p+2)*2 + 1];
        uint4 A3 = csr_ea[(size_t)(p+3)*2], B3 = csr_ea[(size_t)(p+3)*2 + 1];
        float hv0 = h[(size_t)s0 * 64 + lane];
        float hv1 = h[(size_t)s1 * 64 + lane];
        float hv2 = h[(size_t)s2 * 64 + lane];
        float hv3 = h[(size_t)s3 * 64 + lane];
        acc += msg(A0, B0, hv0);
        acc += msg(A1, B1, hv1);
        acc += msg(A2, B2, hv2);
        acc += msg(A3, B3, hv3);
    }
    for (; p < end; ++p) {
        const int s0 = csr_src[p];
        uint4 A = csr_ea[(size_t)p*2], B = csr_ea[(size_t)p*2 + 1];
        float hv = h[(size_t)s0 * 64 + lane];
        acc += msg(A, B, hv);
    }
    out[(size_t)n * 64 + lane] = acc;
}

// ---------------------------------------------------------------------------
// [nrows,64] @ [64,64] + bias GEMM, 2-col register tiling.
// IN_MODE: 0 = in0, 2 = relu(in0*scale+shift)
template<int IN_MODE, bool OUT_RELU, bool OUT_ACCUM>
__global__ __launch_bounds__(256) void gemm64_kernel(
    const float* __restrict__ in0,
    const float* __restrict__ W, const float* __restrict__ bias,
    const float* __restrict__ scale, const float* __restrict__ shift,
    float* __restrict__ out, int nrows,
    float* __restrict__ bn_sum, float* __restrict__ bn_sumsq)
{
    __shared__ __align__(16) float sIn[64*64];
    __shared__ float sRedS[512];
    __shared__ float sRedQ[512];
    const int tid = threadIdx.x;
    const int c  = tid & 31;      // columns c and c+32
    const int rg = tid >> 5;      // 8 row-groups
    const int r0 = blockIdx.x * 64;

    float w0[64], w1[64];
    #pragma unroll
    for (int k = 0; k < 64; ++k) { w0[k] = W[k*64 + c]; w1[k] = W[k*64 + c + 32]; }
    const float b0 = bias[c], b1 = bias[c + 32];

    for (int i = tid; i < 1024; i += 256) {
        const int r  = i >> 4;
        const int c4 = (i & 15) * 4;
        const int gr = r0 + r;
        float4 v = make_float4(0.f, 0.f, 0.f, 0.f);
        if (gr < nrows) {
            v = *(const float4*)(in0 + (size_t)gr*64 + c4);
            if constexpr (IN_MODE == 2) {
                float4 s4 = *(const float4*)(scale + c4);
                float4 h4 = *(const float4*)(shift + c4);
                v.x = fmaxf(fmaf(v.x, s4.x, h4.x), 0.f);
                v.y = fmaxf(fmaf(v.y, s4.y, h4.y), 0.f);
                v.z = fmaxf(fmaf(v.z, s4.z, h4.z), 0.f);
                v.w = fmaxf(fmaf(v.w, s4.w, h4.w), 0.f);
            }
        }
        *(float4*)(sIn + r*64 + c4) = v;
    }
    __syncthreads();

    float ps0 = 0.f, psq0 = 0.f, ps1 = 0.f, psq1 = 0.f;
    #pragma unroll
    for (int i = 0; i < 8; ++i) {
        const int r = rg + 8*i;
        float a0 = b0, a1 = b1;
        #pragma unroll
        for (int k = 0; k < 64; k += 4) {
            float4 a = *(const float4*)(sIn + r*64 + k);
            a0 = fmaf(a.x, w0[k+0], a0); a1 = fmaf(a.x, w1[k+0], a1);
            a0 = fmaf(a.y, w0[k+1], a0); a1 = fmaf(a.y, w1[k+1], a1);
            a0 = fmaf(a.z, w0[k+2], a0); a1 = fmaf(a.z, w1[k+2], a1);
            a0 = fmaf(a.w, w0[k+3], a0); a1 = fmaf(a.w, w1[k+3], a1);
        }
        const int gr = r0 + r;
        if (gr < nrows) {
            if constexpr (OUT_ACCUM) {
                ps0 += a0; psq0 += a0*a0;
                ps1 += a1; psq1 += a1*a1;
            }
            out[(size_t)gr*64 + c]      = OUT_RELU ? fmaxf(a0, 0.f) : a0;
            out[(size_t)gr*64 + c + 32] = OUT_RELU ? fmaxf(a1, 0.f) : a1;
        }
    }

    if constexpr (OUT_ACCUM) {
        sRedS[rg*64 + c]      = ps0;
        sRedS[rg*64 + c + 32] = ps1;
        sRedQ[rg*64 + c]      = psq0;
        sRedQ[rg*64 + c + 32] = psq1;
        __syncthreads();
        if (tid < 64) {
            float s = 0.f, q = 0.f;
            #pragma unroll
            for (int g = 0; g < 8; ++g) { s += sRedS[g*64 + tid]; q += sRedQ[g*64 + tid]; }
            atomicAdd(bn_sum + tid, s);
            atomicAdd(bn_sumsq + tid, q);
        }
    }
}

// ---------------------------------------------------------------------------
__global__ __launch_bounds__(64) void bn_finalize_kernel(
    const float* __restrict__ sum, const float* __restrict__ sumsq,
    const float* __restrict__ gamma, const float* __restrict__ beta,
    float inv_count, float* __restrict__ scale, float* __restrict__ shift)
{
    const int t = threadIdx.x;
    float mu  = sum[t] * inv_count;
    float var = fmaxf(sumsq[t] * inv_count - mu*mu, 0.f);
    float x = var + 1e-5f;
    float r = rsqrtf(x);
    r = r * (1.5f - 0.5f * x * r * r);
    float sc = gamma[t] * r;
    scale[t] = sc;
    shift[t] = beta[t] - mu * sc;
}

// ---------------------------------------------------------------------------
__global__ __launch_bounds__(64) void pool_kernel(
    const float* __restrict__ h, const int* __restrict__ batch,
    float* __restrict__ pooled)
{
    const int g = blockIdx.x;
    const int lane = threadIdx.x;
    int lo = 0, hi = NN;
    while (lo < hi) { int m = (lo + hi) >> 1; if (batch[m] < g) lo = m + 1; else hi = m; }
    const int start = lo;
    hi = NN;
    while (lo < hi) { int m = (lo + hi) >> 1; if (batch[m] < g + 1) lo = m + 1; else hi = m; }
    const int end = lo;
    float acc = 0.f;
    for (int n = start; n < end; ++n) acc += h[(size_t)n*64 + lane];
    pooled[g*64 + lane] = acc;
}

// ---------------------------------------------------------------------------
__global__ __launch_bounds__(256) void head_final_kernel(
    const float* __restrict__ hb, const float* __restrict__ scale,
    const float* __restrict__ shift, const float* __restrict__ fo3_w,
    const float* __restrict__ fo3_b, float* __restrict__ out)
{
    const int idx = blockIdx.x * 256 + threadIdx.x;
    if (idx >= NG * NC) return;
    const int g = idx / NC, c = idx % NC;
    float acc = fo3_b[c];
    for (int k = 0; k < 64; ++k) {
        float v = fmaf(hb[g*64 + k], scale[k], shift[k]);
        acc = fmaf(v, fo3_w[k*NC + c], acc);
    }
    out[idx] = acc;
}

// ---------------------------------------------------------------------------
extern "C" void kernel_launch(void* const* d_in, const int* in_sizes, int n_in,
                              void* d_out, int out_size, void* d_ws, size_t ws_size,
                              hipStream_t stream) {
    const float* x         = (const float*)d_in[0];
    const int*   edge_index= (const int*)  d_in[1];
    const int*   batch     = (const int*)  d_in[2];
    const float* edge_attr = (const float*)d_in[3];
    const float* w_node    = (const float*)d_in[4];
    const float* b_node    = (const float*)d_in[5];
    const float* w_edge    = (const float*)d_in[6];
    const float* b_edge    = (const float*)d_in[7];
    const float* lin_w     = (const float*)d_in[8];
    const float* lin_b     = (const float*)d_in[9];
    const float* mlp1_w    = (const float*)d_in[10];
    const float* mlp1_b    = (const float*)d_in[11];
    const float* bn1_g     = (const float*)d_in[12];
    const float* bn1_b     = (const float*)d_in[13];
    const float* mlp2_w    = (const float*)d_in[14];
    const float* mlp2_b    = (const float*)d_in[15];
    const float* fo1_w     = (const float*)d_in[16];
    const float* fo1_b     = (const float*)d_in[17];
    const float* fo_bn1_g  = (const float*)d_in[18];
    const float* fo_bn1_b  = (const float*)d_in[19];
    const float* fo2_w     = (const float*)d_in[20];
    const float* fo2_b     = (const float*)d_in[21];
    const float* fo_bn2_g  = (const float*)d_in[22];
    const float* fo_bn2_b  = (const float*)d_in[23];
    const float* fo3_w     = (const float*)d_in[24];
    const float* fo3_b     = (const float*)d_in[25];
    float* out = (float*)d_out;

    char* ws = (char*)d_ws;
    float* h    = (float*)(ws);                    // 25.6 MB
    float* agg  = (float*)(ws + 25600000);         // 25.6 MB (CSR-build ints alias here)
    int* counts = (int*)agg;                       // NN ints (dead once layers start)
    int* next   = (int*)agg + NN;                  // NN ints
    int*   csr_src = (int*)(ws + 51200000);        // NE ints (4.8 MB)
    uint4* csr_ea  = (uint4*)(ws + 56000000);      // NE * 32 B bf16 (38.4 MB)
    int* rowptr = (int*)(ws + 94400000);           // NN+1 ints
    float* sm   = (float*)(ws + 94900000);
    float* Wc       = sm;            // 3072
    float* bc       = sm + 3072;     // 192
    float* scale    = sm + 3264;     // 64
    float* shift    = sm + 3328;     // 64
    float* bn_sum   = sm + 3392;     // 64
    float* bn_sumsq = sm + 3456;     // 64
    float* pooled   = sm + 3520;     // 32768
    float* ha       = sm + 36288;    // 32768
    float* hb       = sm + 69056;    // 32768
    int* bsum       = (int*)(sm + 102000);   // NB_SCAN ints
    int* bscan      = bsum + 512;            // NB_SCAN ints

    const int* src = edge_index;
    const int* dst = edge_index + NE;
    float* t = agg;   // alias (safe: per-block read-then-write of own rows)

    const int gemmN_blocks = (NN + 63) / 64;     // 1563
    const int edge_blocks  = (NE + 255) / 256;   // 4688
    const int agg_blocks   = (NN + 3) / 4;       // 25000

    prep_kernel<<<NL, 1024, 0, stream>>>(w_edge, b_edge, lin_w, lin_b, Wc, bc);

    // h = x @ w_node + b_node
    gemm64_kernel<0, false, false><<<gemmN_blocks, 256, 0, stream>>>(
        x, w_node, b_node, nullptr, nullptr, h, NN, nullptr, nullptr);

    // CSR build (per launch; edge_index is an input)
    hipMemsetAsync(counts, 0, NN * sizeof(int), stream);
    hist_kernel<<<edge_blocks, 256, 0, stream>>>(dst, counts);
    scan_reduce_kernel<<<NB_SCAN, 256, 0, stream>>>(counts, bsum);
    scan_partials_kernel<<<1, 512, 0, stream>>>(bsum, bscan);
    scan_final_kernel<<<NB_SCAN, 256, 0, stream>>>(counts, bscan, rowptr, next);
    scatter_kernel<<<edge_blocks, 256, 0, stream>>>(
        src, dst, edge_attr, next, csr_src, csr_ea);

    for (int l = 0; l < NL; ++l) {
        agg_kernel<<<agg_blocks, 256, 0, stream>>>(
            rowptr, csr_src, csr_ea, Wc + l*1024, bc + l*64, h, agg);
        hipMemsetAsync(bn_sum, 0, 128 * sizeof(float), stream);
        gemm64_kernel<0, false, true><<<gemmN_blocks, 256, 0, stream>>>(
            agg, mlp1_w + l*4096, mlp1_b + l*64, nullptr, nullptr,
            t, NN, bn_sum, bn_sumsq);
        bn_finalize_kernel<<<1, 64, 0, stream>>>(
            bn_sum, bn_sumsq, bn1_g + l*64, bn1_b + l*64, 1.0f / NN, scale, shift);
        gemm64_kernel<2, true, false><<<gemmN_blocks, 256, 0, stream>>>(
            t, mlp2_w + l*4096, mlp2_b + l*64, scale, shift,
            h, NN, nullptr, nullptr);
    }

    pool_kernel<<<NG, 64, 0, stream>>>(h, batch, pooled);

    hipMemsetAsync(bn_sum, 0, 128 * sizeof(float), stream);
    gemm64_kernel<0, false, true><<<NG/64, 256, 0, stream>>>(
        pooled, fo1_w, fo1_b, nullptr, nullptr, ha, NG, bn_sum, bn_sumsq);
    bn_finalize_kernel<<<1, 64, 0, stream>>>(
        bn_sum, bn_sumsq, fo_bn1_g, fo_bn1_b, 1.0f / NG, scale, shift);
    hipMemsetAsync(bn_sum, 0, 128 * sizeof(float), stream);
    gemm64_kernel<2, false, true><<<NG/64, 256, 0, stream>>>(
        ha, fo2_w, fo2_b, scale, shift, hb, NG, bn_sum, bn_sumsq);
    bn_finalize_kernel<<<1, 64, 0, stream>>>(
        bn_sum, bn_sumsq, fo_bn2_g, fo_bn2_b, 1.0f / NG, scale, shift);
    head_final_kernel<<<(NG*NC + 255)/256, 256, 0, stream>>>(
        hb, scale, shift, fo3_w, fo3_b, out);
}

// Round 6
// 967.630 us; speedup vs baseline: 12.8196x; 1.0878x over previous
//
#include <hip/hip_runtime.h>

#define NN 100000
#define NE 1200000
#define DD 64
#define EDIM 16
#define NL 3
#define NG 512
#define NC 10
#define NB_SCAN ((NN + 255) / 256)   // 391

typedef _Float16 f16x2 __attribute__((ext_vector_type(2)));

__device__ __forceinline__ unsigned packh2(float a, float b) {
    f16x2 v; v[0] = (_Float16)a; v[1] = (_Float16)b;
    unsigned u; __builtin_memcpy(&u, &v, 4); return u;
}
__device__ __forceinline__ float dot2f(unsigned a, unsigned b, float c) {
    f16x2 av, bv;
    __builtin_memcpy(&av, &a, 4); __builtin_memcpy(&bv, &b, 4);
#if __has_builtin(__builtin_amdgcn_fdot2)
    return __builtin_amdgcn_fdot2(av, bv, c, false);
#else
    return c + (float)av[0]*(float)bv[0] + (float)av[1]*(float)bv[1];
#endif
}

// ---------------------------------------------------------------------------
// prep: Wc[l] = w_edge @ lin_w[l] (16x64) packed to f16 pairs per column;
//       bc[l] = b_edge @ lin_w[l] + lin_b[l]  (fp32)
__global__ __launch_bounds__(1024) void prep_kernel(
    const float* __restrict__ w_edge, const float* __restrict__ b_edge,
    const float* __restrict__ lin_w, const float* __restrict__ lin_b,
    unsigned* __restrict__ Wc16, float* __restrict__ bc)
{
    __shared__ float sWc[1024];
    const int l = blockIdx.x;
    const int tid = threadIdx.x;
    const float* Lw = lin_w + l * 4096;
    const int k = tid >> 6, col = tid & 63;
    float acc = 0.f;
    for (int j = 0; j < 64; ++j) acc = fmaf(w_edge[k*64 + j], Lw[j*64 + col], acc);
    sWc[k*64 + col] = acc;
    if (tid < 64) {
        float a = lin_b[l*64 + tid];
        for (int j = 0; j < 64; ++j) a = fmaf(b_edge[j], Lw[j*64 + tid], a);
        bc[l*64 + tid] = a;
    }
    __syncthreads();
    if (tid < 512) {
        const int j = tid >> 6, c = tid & 63;     // j = pair index (dims 2j,2j+1)
        Wc16[l*512 + j*64 + c] = packh2(sWc[(2*j)*64 + c], sWc[(2*j+1)*64 + c]);
    }
}

// ---------------------------------------------------------------------------
// CSR build: histogram of dst
__global__ __launch_bounds__(256) void hist_kernel(
    const int* __restrict__ dst, int* __restrict__ counts)
{
    const int e = blockIdx.x * 256 + threadIdx.x;
    if (e < NE) atomicAdd(&counts[dst[e]], 1);
}

// ---- multi-block exclusive scan over counts[NN] (3 phases) ----------------
__global__ __launch_bounds__(256) void scan_reduce_kernel(
    const int* __restrict__ counts, int* __restrict__ bsum)
{
    __shared__ int sd[256];
    const int t = threadIdx.x;
    const int idx = blockIdx.x * 256 + t;
    sd[t] = (idx < NN) ? counts[idx] : 0;
    __syncthreads();
    for (int off = 128; off > 0; off >>= 1) {
        if (t < off) sd[t] += sd[t + off];
        __syncthreads();
    }
    if (t == 0) bsum[blockIdx.x] = sd[0];
}

__global__ __launch_bounds__(512) void scan_partials_kernel(
    const int* __restrict__ bsum, int* __restrict__ bscan)
{
    __shared__ int sd[512];
    const int t = threadIdx.x;
    sd[t] = (t < NB_SCAN) ? bsum[t] : 0;
    __syncthreads();
    for (int off = 1; off < 512; off <<= 1) {
        int u = (t >= off) ? sd[t - off] : 0;
        __syncthreads();
        sd[t] += u;
        __syncthreads();
    }
    if (t < NB_SCAN) bscan[t] = (t == 0) ? 0 : sd[t - 1];
}

__global__ __launch_bounds__(256) void scan_final_kernel(
    const int* __restrict__ counts, const int* __restrict__ bscan,
    int* __restrict__ rowptr, int* __restrict__ next)
{
    __shared__ int sd[256];
    const int t = threadIdx.x;
    const int idx = blockIdx.x * 256 + t;
    const int v = (idx < NN) ? counts[idx] : 0;
    sd[t] = v;
    __syncthreads();
    for (int off = 1; off < 256; off <<= 1) {
        int u = (t >= off) ? sd[t - off] : 0;
        __syncthreads();
        sd[t] += u;
        __syncthreads();
    }
    const int excl = sd[t] - v + bscan[blockIdx.x];
    if (idx < NN) { rowptr[idx] = excl; next[idx] = excl; }
    if (idx == NN - 1) rowptr[NN] = excl + v;
}

// scatter: src index + f16-packed edge_attr row into CSR order
__global__ __launch_bounds__(256) void scatter_kernel(
    const int* __restrict__ src, const int* __restrict__ dst,
    const float* __restrict__ edge_attr,
    int* __restrict__ next, int* __restrict__ csr_src, uint4* __restrict__ csr_ea)
{
    const int e = blockIdx.x * 256 + threadIdx.x;
    if (e >= NE) return;
    const float4* q = (const float4*)(edge_attr + (size_t)e * 16);
    float4 a0 = q[0], a1 = q[1], a2 = q[2], a3 = q[3];
    const int pos = atomicAdd(&next[dst[e]], 1);
    csr_src[pos] = src[e];
    uint4 A, B;
    A.x = packh2(a0.x, a0.y); A.y = packh2(a0.z, a0.w);
    A.z = packh2(a1.x, a1.y); A.w = packh2(a1.z, a1.w);
    B.x = packh2(a2.x, a2.y); B.y = packh2(a2.z, a2.w);
    B.z = packh2(a3.x, a3.y); B.w = packh2(a3.z, a3.w);
    csr_ea[(size_t)pos*2 + 0] = A;
    csr_ea[(size_t)pos*2 + 1] = B;
}

// ---------------------------------------------------------------------------
// aggregation: one wave per node, lanes = 64 feature columns.
// Edge MLP via packed-f16 dot2 (fp32 accumulate); h gathered from f16 mirror;
// self-term from fp32 h (exact).
__global__ __launch_bounds__(256) void agg_kernel(
    const int* __restrict__ rowptr, const int* __restrict__ csr_src,
    const uint4* __restrict__ csr_ea,
    const unsigned* __restrict__ Wc16, const float* __restrict__ bc,
    const float* __restrict__ h, const _Float16* __restrict__ h16,
    float* __restrict__ out)
{
    const int tid = threadIdx.x;
    const int lane = tid & 63;
    const int n = blockIdx.x * 4 + (tid >> 6);
    if (n >= NN) return;

    unsigned wq[8];
    #pragma unroll
    for (int j = 0; j < 8; ++j) wq[j] = Wc16[j*64 + lane];
    const float mb = bc[lane];

    const int start = rowptr[n], end = rowptr[n + 1];
    float acc = h[(size_t)n * 64 + lane];          // fused "+ h" (GINE eps=0)

    auto msg = [&](uint4 A, uint4 B, float hv) -> float {
        float m = mb;
        m = dot2f(A.x, wq[0], m); m = dot2f(A.y, wq[1], m);
        m = dot2f(A.z, wq[2], m); m = dot2f(A.w, wq[3], m);
        m = dot2f(B.x, wq[4], m); m = dot2f(B.y, wq[5], m);
        m = dot2f(B.z, wq[6], m); m = dot2f(B.w, wq[7], m);
        return fmaxf(m + hv, 0.f);
    };

    int p = start;
    for (; p + 4 <= end; p += 4) {
        const int s0 = csr_src[p+0], s1 = csr_src[p+1];
        const int s2 = csr_src[p+2], s3 = csr_src[p+3];
        uint4 A0 = csr_ea[(size_t)(p+0)*2], B0 = csr_ea[(size_t)(p+0)*2 + 1];
        uint4 A1 = csr_ea[(size_t)(p+1)*2], B1 = csr_ea[(size_t)(p+1)*2 + 1];
        uint4 A2 = csr_ea[(size_t)(p+2)*2], B2 = csr_ea[(size_t)(p+2)*2 + 1];
        uint4 A3 = csr_ea[(size_t)(p+3)*2], B3 = csr_ea[(size_t)(p+3)*2 + 1];
        float hv0 = (float)h16[(size_t)s0 * 64 + lane];
        float hv1 = (float)h16[(size_t)s1 * 64 + lane];
        float hv2 = (float)h16[(size_t)s2 * 64 + lane];
        float hv3 = (float)h16[(size_t)s3 * 64 + lane];
        acc += msg(A0, B0, hv0);
        acc += msg(A1, B1, hv1);
        acc += msg(A2, B2, hv2);
        acc += msg(A3, B3, hv3);
    }
    for (; p < end; ++p) {
        const int s0 = csr_src[p];
        uint4 A = csr_ea[(size_t)p*2], B = csr_ea[(size_t)p*2 + 1];
        float hv = (float)h16[(size_t)s0 * 64 + lane];
        acc += msg(A, B, hv);
    }
    out[(size_t)n * 64 + lane] = acc;
}

// ---------------------------------------------------------------------------
// [nrows,64] @ [64,64] + bias GEMM, 2-col register tiling.
// IN_MODE: 0 = in0, 2 = relu(in0*scale+shift). OUT_HALF: also write f16 mirror.
template<int IN_MODE, bool OUT_RELU, bool OUT_ACCUM, bool OUT_HALF>
__global__ __launch_bounds__(256) void gemm64_kernel(
    const float* __restrict__ in0,
    const float* __restrict__ W, const float* __restrict__ bias,
    const float* __restrict__ scale, const float* __restrict__ shift,
    float* __restrict__ out, _Float16* __restrict__ out16, int nrows,
    float* __restrict__ bn_sum, float* __restrict__ bn_sumsq)
{
    __shared__ __align__(16) float sIn[64*64];
    __shared__ float sRedS[512];
    __shared__ float sRedQ[512];
    const int tid = threadIdx.x;
    const int c  = tid & 31;      // columns c and c+32
    const int rg = tid >> 5;      // 8 row-groups
    const int r0 = blockIdx.x * 64;

    float w0[64], w1[64];
    #pragma unroll
    for (int k = 0; k < 64; ++k) { w0[k] = W[k*64 + c]; w1[k] = W[k*64 + c + 32]; }
    const float b0 = bias[c], b1 = bias[c + 32];

    for (int i = tid; i < 1024; i += 256) {
        const int r  = i >> 4;
        const int c4 = (i & 15) * 4;
        const int gr = r0 + r;
        float4 v = make_float4(0.f, 0.f, 0.f, 0.f);
        if (gr < nrows) {
            v = *(const float4*)(in0 + (size_t)gr*64 + c4);
            if constexpr (IN_MODE == 2) {
                float4 s4 = *(const float4*)(scale + c4);
                float4 h4 = *(const float4*)(shift + c4);
                v.x = fmaxf(fmaf(v.x, s4.x, h4.x), 0.f);
                v.y = fmaxf(fmaf(v.y, s4.y, h4.y), 0.f);
                v.z = fmaxf(fmaf(v.z, s4.z, h4.z), 0.f);
                v.w = fmaxf(fmaf(v.w, s4.w, h4.w), 0.f);
            }
        }
        *(float4*)(sIn + r*64 + c4) = v;
    }
    __syncthreads();

    float ps0 = 0.f, psq0 = 0.f, ps1 = 0.f, psq1 = 0.f;
    #pragma unroll
    for (int i = 0; i < 8; ++i) {
        const int r = rg + 8*i;
        float a0 = b0, a1 = b1;
        #pragma unroll
        for (int k = 0; k < 64; k += 4) {
            float4 a = *(const float4*)(sIn + r*64 + k);
            a0 = fmaf(a.x, w0[k+0], a0); a1 = fmaf(a.x, w1[k+0], a1);
            a0 = fmaf(a.y, w0[k+1], a0); a1 = fmaf(a.y, w1[k+1], a1);
            a0 = fmaf(a.z, w0[k+2], a0); a1 = fmaf(a.z, w1[k+2], a1);
            a0 = fmaf(a.w, w0[k+3], a0); a1 = fmaf(a.w, w1[k+3], a1);
        }
        const int gr = r0 + r;
        if (gr < nrows) {
            if constexpr (OUT_ACCUM) {
                ps0 += a0; psq0 += a0*a0;
                ps1 += a1; psq1 += a1*a1;
            }
            const float o0 = OUT_RELU ? fmaxf(a0, 0.f) : a0;
            const float o1 = OUT_RELU ? fmaxf(a1, 0.f) : a1;
            out[(size_t)gr*64 + c]      = o0;
            out[(size_t)gr*64 + c + 32] = o1;
            if constexpr (OUT_HALF) {
                out16[(size_t)gr*64 + c]      = (_Float16)o0;
                out16[(size_t)gr*64 + c + 32] = (_Float16)o1;
            }
        }
    }

    if constexpr (OUT_ACCUM) {
        sRedS[rg*64 + c]      = ps0;
        sRedS[rg*64 + c + 32] = ps1;
        sRedQ[rg*64 + c]      = psq0;
        sRedQ[rg*64 + c + 32] = psq1;
        __syncthreads();
        if (tid < 64) {
            float s = 0.f, q = 0.f;
            #pragma unroll
            for (int g = 0; g < 8; ++g) { s += sRedS[g*64 + tid]; q += sRedQ[g*64 + tid]; }
            atomicAdd(bn_sum + tid, s);
            atomicAdd(bn_sumsq + tid, q);
        }
    }
}

// ---------------------------------------------------------------------------
__global__ __launch_bounds__(64) void bn_finalize_kernel(
    const float* __restrict__ sum, const float* __restrict__ sumsq,
    const float* __restrict__ gamma, const float* __restrict__ beta,
    float inv_count, float* __restrict__ scale, float* __restrict__ shift)
{
    const int t = threadIdx.x;
    float mu  = sum[t] * inv_count;
    float var = fmaxf(sumsq[t] * inv_count - mu*mu, 0.f);
    float x = var + 1e-5f;
    float r = rsqrtf(x);
    r = r * (1.5f - 0.5f * x * r * r);
    float sc = gamma[t] * r;
    scale[t] = sc;
    shift[t] = beta[t] - mu * sc;
}

// ---------------------------------------------------------------------------
// global_add_pool: 4 waves per graph
__global__ __launch_bounds__(256) void pool_kernel(
    const float* __restrict__ h, const int* __restrict__ batch,
    float* __restrict__ pooled)
{
    __shared__ float sRed[256];
    const int g = blockIdx.x;
    const int tid = threadIdx.x;
    const int lane = tid & 63, wave = tid >> 6;
    int lo = 0, hi = NN;
    while (lo < hi) { int m = (lo + hi) >> 1; if (batch[m] < g) lo = m + 1; else hi = m; }
    const int start = lo;
    hi = NN;
    while (lo < hi) { int m = (lo + hi) >> 1; if (batch[m] < g + 1) lo = m + 1; else hi = m; }
    const int end = lo;
    float acc = 0.f;
    for (int n = start + wave; n < end; n += 4) acc += h[(size_t)n*64 + lane];
    sRed[tid] = acc;
    __syncthreads();
    if (tid < 64)
        pooled[g*64 + tid] = sRed[tid] + sRed[64+tid] + sRed[128+tid] + sRed[192+tid];
}

// ---------------------------------------------------------------------------
__global__ __launch_bounds__(256) void head_final_kernel(
    const float* __restrict__ hb, const float* __restrict__ scale,
    const float* __restrict__ shift, const float* __restrict__ fo3_w,
    const float* __restrict__ fo3_b, float* __restrict__ out)
{
    const int idx = blockIdx.x * 256 + threadIdx.x;
    if (idx >= NG * NC) return;
    const int g = idx / NC, c = idx % NC;
    float acc = fo3_b[c];
    for (int k = 0; k < 64; ++k) {
        float v = fmaf(hb[g*64 + k], scale[k], shift[k]);
        acc = fmaf(v, fo3_w[k*NC + c], acc);
    }
    out[idx] = acc;
}

// ---------------------------------------------------------------------------
extern "C" void kernel_launch(void* const* d_in, const int* in_sizes, int n_in,
                              void* d_out, int out_size, void* d_ws, size_t ws_size,
                              hipStream_t stream) {
    const float* x         = (const float*)d_in[0];
    const int*   edge_index= (const int*)  d_in[1];
    const int*   batch     = (const int*)  d_in[2];
    const float* edge_attr = (const float*)d_in[3];
    const float* w_node    = (const float*)d_in[4];
    const float* b_node    = (const float*)d_in[5];
    const float* w_edge    = (const float*)d_in[6];
    const float* b_edge    = (const float*)d_in[7];
    const float* lin_w     = (const float*)d_in[8];
    const float* lin_b     = (const float*)d_in[9];
    const float* mlp1_w    = (const float*)d_in[10];
    const float* mlp1_b    = (const float*)d_in[11];
    const float* bn1_g     = (const float*)d_in[12];
    const float* bn1_b     = (const float*)d_in[13];
    const float* mlp2_w    = (const float*)d_in[14];
    const float* mlp2_b    = (const float*)d_in[15];
    const float* fo1_w     = (const float*)d_in[16];
    const float* fo1_b     = (const float*)d_in[17];
    const float* fo_bn1_g  = (const float*)d_in[18];
    const float* fo_bn1_b  = (const float*)d_in[19];
    const float* fo2_w     = (const float*)d_in[20];
    const float* fo2_b     = (const float*)d_in[21];
    const float* fo_bn2_g  = (const float*)d_in[22];
    const float* fo_bn2_b  = (const float*)d_in[23];
    const float* fo3_w     = (const float*)d_in[24];
    const float* fo3_b     = (const float*)d_in[25];
    float* out = (float*)d_out;

    char* ws = (char*)d_ws;
    float* h    = (float*)(ws);                    // 25.6 MB
    float* agg  = (float*)(ws + 25600000);         // 25.6 MB (CSR-build ints alias here)
    int* counts = (int*)agg;                       // NN ints (dead once layers start)
    int* next   = (int*)agg + NN;                  // NN ints
    int*   csr_src = (int*)(ws + 51200000);        // NE ints (4.8 MB)
    uint4* csr_ea  = (uint4*)(ws + 56000000);      // NE * 32 B f16 (38.4 MB)
    int* rowptr = (int*)(ws + 94400000);           // NN+1 ints
    _Float16* h16 = (_Float16*)(ws + 94900000);    // NN*64 f16 (12.8 MB)
    float* sm   = (float*)(ws + 107700000);
    unsigned* Wc16 = (unsigned*)sm;  // 3*512 uints
    float* bc       = sm + 1536;     // 192
    float* scale    = sm + 1728;     // 64
    float* shift    = sm + 1792;     // 64
    float* bn_sum   = sm + 1856;     // 64
    float* bn_sumsq = sm + 1920;     // 64
    float* pooled   = sm + 1984;     // 32768
    float* ha       = sm + 34752;    // 32768
    float* hb       = sm + 67520;    // 32768
    int* bsum       = (int*)(sm + 100288);   // NB_SCAN ints
    int* bscan      = bsum + 512;            // NB_SCAN ints

    const int* src = edge_index;
    const int* dst = edge_index + NE;
    float* t = agg;   // alias (safe: per-block read-then-write of own rows)

    const int gemmN_blocks = (NN + 63) / 64;     // 1563
    const int edge_blocks  = (NE + 255) / 256;   // 4688
    const int agg_blocks   = (NN + 3) / 4;       // 25000

    prep_kernel<<<NL, 1024, 0, stream>>>(w_edge, b_edge, lin_w, lin_b, Wc16, bc);

    // h = x @ w_node + b_node  (+ f16 mirror)
    gemm64_kernel<0, false, false, true><<<gemmN_blocks, 256, 0, stream>>>(
        x, w_node, b_node, nullptr, nullptr, h, h16, NN, nullptr, nullptr);

    // CSR build (per launch; edge_index is an input)
    hipMemsetAsync(counts, 0, NN * sizeof(int), stream);
    hist_kernel<<<edge_blocks, 256, 0, stream>>>(dst, counts);
    scan_reduce_kernel<<<NB_SCAN, 256, 0, stream>>>(counts, bsum);
    scan_partials_kernel<<<1, 512, 0, stream>>>(bsum, bscan);
    scan_final_kernel<<<NB_SCAN, 256, 0, stream>>>(counts, bscan, rowptr, next);
    scatter_kernel<<<edge_blocks, 256, 0, stream>>>(
        src, dst, edge_attr, next, csr_src, csr_ea);

    for (int l = 0; l < NL; ++l) {
        agg_kernel<<<agg_blocks, 256, 0, stream>>>(
            rowptr, csr_src, csr_ea, Wc16 + l*512, bc + l*64, h, h16, agg);
        hipMemsetAsync(bn_sum, 0, 128 * sizeof(float), stream);
        gemm64_kernel<0, false, true, false><<<gemmN_blocks, 256, 0, stream>>>(
            agg, mlp1_w + l*4096, mlp1_b + l*64, nullptr, nullptr,
            t, nullptr, NN, bn_sum, bn_sumsq);
        bn_finalize_kernel<<<1, 64, 0, stream>>>(
            bn_sum, bn_sumsq, bn1_g + l*64, bn1_b + l*64, 1.0f / NN, scale, shift);
        gemm64_kernel<2, true, false, true><<<gemmN_blocks, 256, 0, stream>>>(
            t, mlp2_w + l*4096, mlp2_b + l*64, scale, shift,
            h, h16, NN, nullptr, nullptr);
    }

    pool_kernel<<<NG, 256, 0, stream>>>(h, batch, pooled);

    hipMemsetAsync(bn_sum, 0, 128 * sizeof(float), stream);
    gemm64_kernel<0, false, true, false><<<NG/64, 256, 0, stream>>>(
        pooled, fo1_w, fo1_b, nullptr, nullptr, ha, nullptr, NG, bn_sum, bn_sumsq);
    bn_finalize_kernel<<<1, 64, 0, stream>>>(
        bn_sum, bn_sumsq, fo_bn1_g, fo_bn1_b, 1.0f / NG, scale, shift);
    hipMemsetAsync(bn_sum, 0, 128 * sizeof(float), stream);
    gemm64_kernel<2, false, true, false><<<NG/64, 256, 0, stream>>>(
        ha, fo2_w, fo2_b, scale, shift, hb, nullptr, NG, bn_sum, bn_sumsq);
    bn_finalize_kernel<<<1, 64, 0, stream>>>(
        bn_sum, bn_sumsq, fo_bn2_g, fo_bn2_b, 1.0f / NG, scale, shift);
    head_final_kernel<<<(NG*NC + 255)/256, 256, 0, stream>>>(
        hb, scale, shift, fo3_w, fo3_b, out);
}

// Round 7
// 884.614 us; speedup vs baseline: 14.0226x; 1.0938x over previous
//
#include <hip/hip_runtime.h>

#define NN 100000
#define NE 1200000
#define DD 64
#define EDIM 16
#define NL 3
#define NG 512
#define NC 10
#define NB_SCAN ((NN + 255) / 256)   // 391

typedef _Float16 f16x2 __attribute__((ext_vector_type(2)));
typedef _Float16 v8h   __attribute__((ext_vector_type(8)));
typedef float    v4f   __attribute__((ext_vector_type(4)));

__device__ __forceinline__ unsigned packh2(float a, float b) {
    f16x2 v; v[0] = (_Float16)a; v[1] = (_Float16)b;
    unsigned u; __builtin_memcpy(&u, &v, 4); return u;
}
__device__ __forceinline__ float dot2f(unsigned a, unsigned b, float c) {
    f16x2 av, bv;
    __builtin_memcpy(&av, &a, 4); __builtin_memcpy(&bv, &b, 4);
#if __has_builtin(__builtin_amdgcn_fdot2)
    return __builtin_amdgcn_fdot2(av, bv, c, false);
#else
    return c + (float)av[0]*(float)bv[0] + (float)av[1]*(float)bv[1];
#endif
}

// ---------------------------------------------------------------------------
// prep: Wc[l] = w_edge @ lin_w[l] (16x64) packed to f16 pairs per column;
//       bc[l] = b_edge @ lin_w[l] + lin_b[l]  (fp32)
__global__ __launch_bounds__(1024) void prep_kernel(
    const float* __restrict__ w_edge, const float* __restrict__ b_edge,
    const float* __restrict__ lin_w, const float* __restrict__ lin_b,
    unsigned* __restrict__ Wc16, float* __restrict__ bc)
{
    __shared__ float sWc[1024];
    const int l = blockIdx.x;
    const int tid = threadIdx.x;
    const float* Lw = lin_w + l * 4096;
    const int k = tid >> 6, col = tid & 63;
    float acc = 0.f;
    for (int j = 0; j < 64; ++j) acc = fmaf(w_edge[k*64 + j], Lw[j*64 + col], acc);
    sWc[k*64 + col] = acc;
    if (tid < 64) {
        float a = lin_b[l*64 + tid];
        for (int j = 0; j < 64; ++j) a = fmaf(b_edge[j], Lw[j*64 + tid], a);
        bc[l*64 + tid] = a;
    }
    __syncthreads();
    if (tid < 512) {
        const int j = tid >> 6, c = tid & 63;     // j = pair index (dims 2j,2j+1)
        Wc16[l*512 + j*64 + c] = packh2(sWc[(2*j)*64 + c], sWc[(2*j+1)*64 + c]);
    }
}

// ---------------------------------------------------------------------------
// pack node-GEMM weights [64x64] fp32 -> f16 MFMA B-fragment order.
// m: 0 = w_node, 1..3 = mlp1_w[l], 4..6 = mlp2_w[l]
// fragment fid = tile*2 + kfrag; lane l: n = (l&15)+16*tile, k = kfrag*32+(l>>4)*8+j
__global__ __launch_bounds__(512) void pack_w_kernel(
    const float* __restrict__ w_node, const float* __restrict__ mlp1_w,
    const float* __restrict__ mlp2_w, v8h* __restrict__ Wpk)
{
    const int m = blockIdx.x;
    const float* W = (m == 0) ? w_node
                   : (m <= 3) ? mlp1_w + (m-1)*4096
                              : mlp2_w + (m-4)*4096;
    const int fid = threadIdx.x >> 6;
    const int l   = threadIdx.x & 63;
    const int t = fid >> 1, f = fid & 1;
    const int n  = (l & 15) + 16*t;
    const int kb = f*32 + (l >> 4)*8;
    v8h v;
    #pragma unroll
    for (int j = 0; j < 8; ++j) v[j] = (_Float16)W[(kb + j)*64 + n];
    Wpk[m*512 + fid*64 + l] = v;
}

// ---------------------------------------------------------------------------
// CSR build: histogram of dst
__global__ __launch_bounds__(256) void hist_kernel(
    const int* __restrict__ dst, int* __restrict__ counts)
{
    const int e = blockIdx.x * 256 + threadIdx.x;
    if (e < NE) atomicAdd(&counts[dst[e]], 1);
}

// ---- multi-block exclusive scan over counts[NN] (3 phases) ----------------
__global__ __launch_bounds__(256) void scan_reduce_kernel(
    const int* __restrict__ counts, int* __restrict__ bsum)
{
    __shared__ int sd[256];
    const int t = threadIdx.x;
    const int idx = blockIdx.x * 256 + t;
    sd[t] = (idx < NN) ? counts[idx] : 0;
    __syncthreads();
    for (int off = 128; off > 0; off >>= 1) {
        if (t < off) sd[t] += sd[t + off];
        __syncthreads();
    }
    if (t == 0) bsum[blockIdx.x] = sd[0];
}

__global__ __launch_bounds__(512) void scan_partials_kernel(
    const int* __restrict__ bsum, int* __restrict__ bscan)
{
    __shared__ int sd[512];
    const int t = threadIdx.x;
    sd[t] = (t < NB_SCAN) ? bsum[t] : 0;
    __syncthreads();
    for (int off = 1; off < 512; off <<= 1) {
        int u = (t >= off) ? sd[t - off] : 0;
        __syncthreads();
        sd[t] += u;
        __syncthreads();
    }
    if (t < NB_SCAN) bscan[t] = (t == 0) ? 0 : sd[t - 1];
}

__global__ __launch_bounds__(256) void scan_final_kernel(
    const int* __restrict__ counts, const int* __restrict__ bscan,
    int* __restrict__ rowptr, int* __restrict__ next)
{
    __shared__ int sd[256];
    const int t = threadIdx.x;
    const int idx = blockIdx.x * 256 + t;
    const int v = (idx < NN) ? counts[idx] : 0;
    sd[t] = v;
    __syncthreads();
    for (int off = 1; off < 256; off <<= 1) {
        int u = (t >= off) ? sd[t - off] : 0;
        __syncthreads();
        sd[t] += u;
        __syncthreads();
    }
    const int excl = sd[t] - v + bscan[blockIdx.x];
    if (idx < NN) { rowptr[idx] = excl; next[idx] = excl; }
    if (idx == NN - 1) rowptr[NN] = excl + v;
}

// scatter: src index + f16-packed edge_attr row into CSR order
__global__ __launch_bounds__(256) void scatter_kernel(
    const int* __restrict__ src, const int* __restrict__ dst,
    const float* __restrict__ edge_attr,
    int* __restrict__ next, int* __restrict__ csr_src, uint4* __restrict__ csr_ea)
{
    const int e = blockIdx.x * 256 + threadIdx.x;
    if (e >= NE) return;
    const float4* q = (const float4*)(edge_attr + (size_t)e * 16);
    float4 a0 = q[0], a1 = q[1], a2 = q[2], a3 = q[3];
    const int pos = atomicAdd(&next[dst[e]], 1);
    csr_src[pos] = src[e];
    uint4 A, B;
    A.x = packh2(a0.x, a0.y); A.y = packh2(a0.z, a0.w);
    A.z = packh2(a1.x, a1.y); A.w = packh2(a1.z, a1.w);
    B.x = packh2(a2.x, a2.y); B.y = packh2(a2.z, a2.w);
    B.z = packh2(a3.x, a3.y); B.w = packh2(a3.z, a3.w);
    csr_ea[(size_t)pos*2 + 0] = A;
    csr_ea[(size_t)pos*2 + 1] = B;
}

// ---------------------------------------------------------------------------
// aggregation: one wave per node, lanes = 64 feature columns.
// Output ONLY f16 (mlp1's MFMA A-operand); self-term from fp32 h (exact).
__global__ __launch_bounds__(256) void agg_kernel(
    const int* __restrict__ rowptr, const int* __restrict__ csr_src,
    const uint4* __restrict__ csr_ea,
    const unsigned* __restrict__ Wc16, const float* __restrict__ bc,
    const float* __restrict__ h, const _Float16* __restrict__ h16,
    _Float16* __restrict__ out16)
{
    const int tid = threadIdx.x;
    const int lane = tid & 63;
    const int n = blockIdx.x * 4 + (tid >> 6);
    if (n >= NN) return;

    unsigned wq[8];
    #pragma unroll
    for (int j = 0; j < 8; ++j) wq[j] = Wc16[j*64 + lane];
    const float mb = bc[lane];

    const int start = rowptr[n], end = rowptr[n + 1];
    float acc = h[(size_t)n * 64 + lane];          // fused "+ h" (GINE eps=0)

    auto msg = [&](uint4 A, uint4 B, float hv) -> float {
        float m = mb;
        m = dot2f(A.x, wq[0], m); m = dot2f(A.y, wq[1], m);
        m = dot2f(A.z, wq[2], m); m = dot2f(A.w, wq[3], m);
        m = dot2f(B.x, wq[4], m); m = dot2f(B.y, wq[5], m);
        m = dot2f(B.z, wq[6], m); m = dot2f(B.w, wq[7], m);
        return fmaxf(m + hv, 0.f);
    };

    int p = start;
    for (; p + 4 <= end; p += 4) {
        const int s0 = csr_src[p+0], s1 = csr_src[p+1];
        const int s2 = csr_src[p+2], s3 = csr_src[p+3];
        uint4 A0 = csr_ea[(size_t)(p+0)*2], B0 = csr_ea[(size_t)(p+0)*2 + 1];
        uint4 A1 = csr_ea[(size_t)(p+1)*2], B1 = csr_ea[(size_t)(p+1)*2 + 1];
        uint4 A2 = csr_ea[(size_t)(p+2)*2], B2 = csr_ea[(size_t)(p+2)*2 + 1];
        uint4 A3 = csr_ea[(size_t)(p+3)*2], B3 = csr_ea[(size_t)(p+3)*2 + 1];
        float hv0 = (float)h16[(size_t)s0 * 64 + lane];
        float hv1 = (float)h16[(size_t)s1 * 64 + lane];
        float hv2 = (float)h16[(size_t)s2 * 64 + lane];
        float hv3 = (float)h16[(size_t)s3 * 64 + lane];
        acc += msg(A0, B0, hv0);
        acc += msg(A1, B1, hv1);
        acc += msg(A2, B2, hv2);
        acc += msg(A3, B3, hv3);
    }
    for (; p < end; ++p) {
        const int s0 = csr_src[p];
        uint4 A = csr_ea[(size_t)p*2], B = csr_ea[(size_t)p*2 + 1];
        float hv = (float)h16[(size_t)s0 * 64 + lane];
        acc += msg(A, B, hv);
    }
    out16[(size_t)n * 64 + lane] = (_Float16)acc;
}

// ---------------------------------------------------------------------------
// MFMA node GEMM: [NN,64] @ [64,64] + bias.
// One wave = 16 rows x 64 cols (4 C-tiles, K=64 -> 2 mfma/tile).
// Layouts (gfx950, m89/m120-verified): A[m=lane&15][k=quad*8+j],
// B[k=quad*8+j][n=lane&15] (pre-packed), C/D col=lane&15 row=quad*4+reg.
// IN_HALF: A from f16; else fp32 (+ relu(a*scale+shift) if TRANS).
template<bool IN_HALF, bool TRANS, bool OUT_RELU, bool OUT_ACCUM, bool OUT_HALF>
__global__ __launch_bounds__(256) void mfma_gemm_kernel(
    const float* __restrict__ in0, const _Float16* __restrict__ in16,
    const v8h* __restrict__ Wpk, const float* __restrict__ bias,
    const float* __restrict__ scale, const float* __restrict__ shift,
    float* __restrict__ out, _Float16* __restrict__ out16,
    float* __restrict__ bn_sum, float* __restrict__ bn_sumsq)
{
    __shared__ float sS[1024];
    __shared__ float sQ[1024];
    const int tid = threadIdx.x;
    const int wv = tid >> 6, l = tid & 63;
    const int li = l & 15, quad = l >> 4;
    const int rb = (blockIdx.x * 4 + wv) * 16;   // row-block base
    const bool active = (rb < NN);               // NN % 16 == 0

    v8h Bf[8];
    #pragma unroll
    for (int i = 0; i < 8; ++i) Bf[i] = Wpk[i*64 + l];

    v4f acc[4] = {v4f{0,0,0,0}, v4f{0,0,0,0}, v4f{0,0,0,0}, v4f{0,0,0,0}};

    if (active) {
        v8h Af[2];
        if constexpr (IN_HALF) {
            const _Float16* arow = in16 + (size_t)(rb + li)*64 + quad*8;
            Af[0] = *(const v8h*)(arow);
            Af[1] = *(const v8h*)(arow + 32);
        } else {
            const float* arow = in0 + (size_t)(rb + li)*64 + quad*8;
            #pragma unroll
            for (int f = 0; f < 2; ++f) {
                float4 x0 = *(const float4*)(arow + f*32);
                float4 x1 = *(const float4*)(arow + f*32 + 4);
                if constexpr (TRANS) {
                    const int kb = f*32 + quad*8;
                    float4 s0 = *(const float4*)(scale + kb);
                    float4 s1 = *(const float4*)(scale + kb + 4);
                    float4 t0 = *(const float4*)(shift + kb);
                    float4 t1 = *(const float4*)(shift + kb + 4);
                    x0.x = fmaxf(fmaf(x0.x, s0.x, t0.x), 0.f);
                    x0.y = fmaxf(fmaf(x0.y, s0.y, t0.y), 0.f);
                    x0.z = fmaxf(fmaf(x0.z, s0.z, t0.z), 0.f);
                    x0.w = fmaxf(fmaf(x0.w, s0.w, t0.w), 0.f);
                    x1.x = fmaxf(fmaf(x1.x, s1.x, t1.x), 0.f);
                    x1.y = fmaxf(fmaf(x1.y, s1.y, t1.y), 0.f);
                    x1.z = fmaxf(fmaf(x1.z, s1.z, t1.z), 0.f);
                    x1.w = fmaxf(fmaf(x1.w, s1.w, t1.w), 0.f);
                }
                v8h a;
                a[0] = (_Float16)x0.x; a[1] = (_Float16)x0.y;
                a[2] = (_Float16)x0.z; a[3] = (_Float16)x0.w;
                a[4] = (_Float16)x1.x; a[5] = (_Float16)x1.y;
                a[6] = (_Float16)x1.z; a[7] = (_Float16)x1.w;
                Af[f] = a;
            }
        }
        #pragma unroll
        for (int t = 0; t < 4; ++t) {
            acc[t] = __builtin_amdgcn_mfma_f32_16x16x32_f16(Af[0], Bf[t*2+0], acc[t], 0, 0, 0);
            acc[t] = __builtin_amdgcn_mfma_f32_16x16x32_f16(Af[1], Bf[t*2+1], acc[t], 0, 0, 0);
        }
    }

    float ps[4] = {0.f, 0.f, 0.f, 0.f}, pq[4] = {0.f, 0.f, 0.f, 0.f};
    if (active) {
        #pragma unroll
        for (int t = 0; t < 4; ++t) {
            const int col = li + 16*t;
            const float bcol = bias[col];
            #pragma unroll
            for (int r = 0; r < 4; ++r) {
                const int row = rb + quad*4 + r;
                float v = acc[t][r] + bcol;
                if constexpr (OUT_ACCUM) { ps[t] += v; pq[t] += v*v; }
                if constexpr (OUT_RELU) v = fmaxf(v, 0.f);
                out[(size_t)row*64 + col] = v;
                if constexpr (OUT_HALF) out16[(size_t)row*64 + col] = (_Float16)v;
            }
        }
    }

    if constexpr (OUT_ACCUM) {
        #pragma unroll
        for (int t = 0; t < 4; ++t) {
            sS[wv*256 + l*4 + t] = ps[t];
            sQ[wv*256 + l*4 + t] = pq[t];
        }
        __syncthreads();
        if (tid < 64) {
            const int t = tid >> 4, li2 = tid & 15;
            float s = 0.f, q = 0.f;
            #pragma unroll
            for (int w = 0; w < 4; ++w)
                #pragma unroll
                for (int qd = 0; qd < 4; ++qd) {
                    const int idx = w*256 + (qd*16 + li2)*4 + t;
                    s += sS[idx]; q += sQ[idx];
                }
            atomicAdd(bn_sum + tid, s);
            atomicAdd(bn_sumsq + tid, q);
        }
    }
}

// ---------------------------------------------------------------------------
// small vector GEMM for the 512-row head (unchanged structure)
template<int IN_MODE, bool OUT_RELU, bool OUT_ACCUM>
__global__ __launch_bounds__(256) void gemm64_kernel(
    const float* __restrict__ in0,
    const float* __restrict__ W, const float* __restrict__ bias,
    const float* __restrict__ scale, const float* __restrict__ shift,
    float* __restrict__ out, int nrows,
    float* __restrict__ bn_sum, float* __restrict__ bn_sumsq)
{
    __shared__ __align__(16) float sIn[64*64];
    __shared__ float sRedS[512];
    __shared__ float sRedQ[512];
    const int tid = threadIdx.x;
    const int c  = tid & 31;
    const int rg = tid >> 5;
    const int r0 = blockIdx.x * 64;

    float w0[64], w1[64];
    #pragma unroll
    for (int k = 0; k < 64; ++k) { w0[k] = W[k*64 + c]; w1[k] = W[k*64 + c + 32]; }
    const float b0 = bias[c], b1 = bias[c + 32];

    for (int i = tid; i < 1024; i += 256) {
        const int r  = i >> 4;
        const int c4 = (i & 15) * 4;
        const int gr = r0 + r;
        float4 v = make_float4(0.f, 0.f, 0.f, 0.f);
        if (gr < nrows) {
            v = *(const float4*)(in0 + (size_t)gr*64 + c4);
            if constexpr (IN_MODE == 2) {
                float4 s4 = *(const float4*)(scale + c4);
                float4 h4 = *(const float4*)(shift + c4);
                v.x = fmaxf(fmaf(v.x, s4.x, h4.x), 0.f);
                v.y = fmaxf(fmaf(v.y, s4.y, h4.y), 0.f);
                v.z = fmaxf(fmaf(v.z, s4.z, h4.z), 0.f);
                v.w = fmaxf(fmaf(v.w, s4.w, h4.w), 0.f);
            }
        }
        *(float4*)(sIn + r*64 + c4) = v;
    }
    __syncthreads();

    float ps0 = 0.f, psq0 = 0.f, ps1 = 0.f, psq1 = 0.f;
    #pragma unroll
    for (int i = 0; i < 8; ++i) {
        const int r = rg + 8*i;
        float a0 = b0, a1 = b1;
        #pragma unroll
        for (int k = 0; k < 64; k += 4) {
            float4 a = *(const float4*)(sIn + r*64 + k);
            a0 = fmaf(a.x, w0[k+0], a0); a1 = fmaf(a.x, w1[k+0], a1);
            a0 = fmaf(a.y, w0[k+1], a0); a1 = fmaf(a.y, w1[k+1], a1);
            a0 = fmaf(a.z, w0[k+2], a0); a1 = fmaf(a.z, w1[k+2], a1);
            a0 = fmaf(a.w, w0[k+3], a0); a1 = fmaf(a.w, w1[k+3], a1);
        }
        const int gr = r0 + r;
        if (gr < nrows) {
            if constexpr (OUT_ACCUM) {
                ps0 += a0; psq0 += a0*a0;
                ps1 += a1; psq1 += a1*a1;
            }
            out[(size_t)gr*64 + c]      = OUT_RELU ? fmaxf(a0, 0.f) : a0;
            out[(size_t)gr*64 + c + 32] = OUT_RELU ? fmaxf(a1, 0.f) : a1;
        }
    }

    if constexpr (OUT_ACCUM) {
        sRedS[rg*64 + c]      = ps0;
        sRedS[rg*64 + c + 32] = ps1;
        sRedQ[rg*64 + c]      = psq0;
        sRedQ[rg*64 + c + 32] = psq1;
        __syncthreads();
        if (tid < 64) {
            float s = 0.f, q = 0.f;
            #pragma unroll
            for (int g = 0; g < 8; ++g) { s += sRedS[g*64 + tid]; q += sRedQ[g*64 + tid]; }
            atomicAdd(bn_sum + tid, s);
            atomicAdd(bn_sumsq + tid, q);
        }
    }
}

// ---------------------------------------------------------------------------
__global__ __launch_bounds__(64) void bn_finalize_kernel(
    const float* __restrict__ sum, const float* __restrict__ sumsq,
    const float* __restrict__ gamma, const float* __restrict__ beta,
    float inv_count, float* __restrict__ scale, float* __restrict__ shift)
{
    const int t = threadIdx.x;
    float mu  = sum[t] * inv_count;
    float var = fmaxf(sumsq[t] * inv_count - mu*mu, 0.f);
    float x = var + 1e-5f;
    float r = rsqrtf(x);
    r = r * (1.5f - 0.5f * x * r * r);
    float sc = gamma[t] * r;
    scale[t] = sc;
    shift[t] = beta[t] - mu * sc;
}

// ---------------------------------------------------------------------------
__global__ __launch_bounds__(256) void pool_kernel(
    const float* __restrict__ h, const int* __restrict__ batch,
    float* __restrict__ pooled)
{
    __shared__ float sRed[256];
    const int g = blockIdx.x;
    const int tid = threadIdx.x;
    const int lane = tid & 63, wave = tid >> 6;
    int lo = 0, hi = NN;
    while (lo < hi) { int m = (lo + hi) >> 1; if (batch[m] < g) lo = m + 1; else hi = m; }
    const int start = lo;
    hi = NN;
    while (lo < hi) { int m = (lo + hi) >> 1; if (batch[m] < g + 1) lo = m + 1; else hi = m; }
    const int end = lo;
    float acc = 0.f;
    for (int n = start + wave; n < end; n += 4) acc += h[(size_t)n*64 + lane];
    sRed[tid] = acc;
    __syncthreads();
    if (tid < 64)
        pooled[g*64 + tid] = sRed[tid] + sRed[64+tid] + sRed[128+tid] + sRed[192+tid];
}

// ---------------------------------------------------------------------------
__global__ __launch_bounds__(256) void head_final_kernel(
    const float* __restrict__ hb, const float* __restrict__ scale,
    const float* __restrict__ shift, const float* __restrict__ fo3_w,
    const float* __restrict__ fo3_b, float* __restrict__ out)
{
    const int idx = blockIdx.x * 256 + threadIdx.x;
    if (idx >= NG * NC) return;
    const int g = idx / NC, c = idx % NC;
    float acc = fo3_b[c];
    for (int k = 0; k < 64; ++k) {
        float v = fmaf(hb[g*64 + k], scale[k], shift[k]);
        acc = fmaf(v, fo3_w[k*NC + c], acc);
    }
    out[idx] = acc;
}

// ---------------------------------------------------------------------------
extern "C" void kernel_launch(void* const* d_in, const int* in_sizes, int n_in,
                              void* d_out, int out_size, void* d_ws, size_t ws_size,
                              hipStream_t stream) {
    const float* x         = (const float*)d_in[0];
    const int*   edge_index= (const int*)  d_in[1];
    const int*   batch     = (const int*)  d_in[2];
    const float* edge_attr = (const float*)d_in[3];
    const float* w_node    = (const float*)d_in[4];
    const float* b_node    = (const float*)d_in[5];
    const float* w_edge    = (const float*)d_in[6];
    const float* b_edge    = (const float*)d_in[7];
    const float* lin_w     = (const float*)d_in[8];
    const float* lin_b     = (const float*)d_in[9];
    const float* mlp1_w    = (const float*)d_in[10];
    const float* mlp1_b    = (const float*)d_in[11];
    const float* bn1_g     = (const float*)d_in[12];
    const float* bn1_b     = (const float*)d_in[13];
    const float* mlp2_w    = (const float*)d_in[14];
    const float* mlp2_b    = (const float*)d_in[15];
    const float* fo1_w     = (const float*)d_in[16];
    const float* fo1_b     = (const float*)d_in[17];
    const float* fo_bn1_g  = (const float*)d_in[18];
    const float* fo_bn1_b  = (const float*)d_in[19];
    const float* fo2_w     = (const float*)d_in[20];
    const float* fo2_b     = (const float*)d_in[21];
    const float* fo_bn2_g  = (const float*)d_in[22];
    const float* fo_bn2_b  = (const float*)d_in[23];
    const float* fo3_w     = (const float*)d_in[24];
    const float* fo3_b     = (const float*)d_in[25];
    float* out = (float*)d_out;

    char* ws = (char*)d_ws;
    float* h    = (float*)(ws);                    // 25.6 MB
    float* t    = (float*)(ws + 25600000);         // 25.6 MB (CSR-build ints alias)
    int* counts = (int*)t;                         // NN ints (dead before t written)
    int* next   = (int*)t + NN;                    // NN ints (dead after scatter)
    int*   csr_src = (int*)(ws + 51200000);        // 4.8 MB
    uint4* csr_ea  = (uint4*)(ws + 56000000);      // 38.4 MB
    int* rowptr = (int*)(ws + 94400000);           // NN+1 ints
    _Float16* h16   = (_Float16*)(ws + 94900000);  // 12.8 MB
    _Float16* agg16 = (_Float16*)(ws + 107700000); // 12.8 MB
    float* sm   = (float*)(ws + 120500000);
    unsigned* Wc16 = (unsigned*)sm;  // 3*512 uints (edge weights f16)
    float* bc       = sm + 1536;     // 192
    float* scale    = sm + 1728;     // 64
    float* shift    = sm + 1792;     // 64
    float* bn_sum   = sm + 1856;     // 64
    float* bn_sumsq = sm + 1920;     // 64
    float* pooled   = sm + 1984;     // 32768
    float* ha       = sm + 34752;    // 32768
    float* hb       = sm + 67520;    // 32768
    int* bsum       = (int*)(sm + 100288);   // NB_SCAN ints
    int* bscan      = bsum + 512;
    v8h* Wpk        = (v8h*)(sm + 101376);   // 7*512*16 B (16B-aligned)

    const int* src = edge_index;
    const int* dst = edge_index + NE;

    const int mfma_blocks  = (NN/16 + 3) / 4;    // 1563 (6250 row-blocks)
    const int edge_blocks  = (NE + 255) / 256;   // 4688
    const int agg_blocks   = (NN + 3) / 4;       // 25000

    prep_kernel<<<NL, 1024, 0, stream>>>(w_edge, b_edge, lin_w, lin_b, Wc16, bc);
    pack_w_kernel<<<7, 512, 0, stream>>>(w_node, mlp1_w, mlp2_w, Wpk);

    // h = x @ w_node + b_node  (fp32 + f16 mirror)
    mfma_gemm_kernel<false, false, false, false, true><<<mfma_blocks, 256, 0, stream>>>(
        x, nullptr, Wpk, b_node, nullptr, nullptr, h, h16, nullptr, nullptr);

    // CSR build (per launch; edge_index is an input)
    hipMemsetAsync(counts, 0, NN * sizeof(int), stream);
    hist_kernel<<<edge_blocks, 256, 0, stream>>>(dst, counts);
    scan_reduce_kernel<<<NB_SCAN, 256, 0, stream>>>(counts, bsum);
    scan_partials_kernel<<<1, 512, 0, stream>>>(bsum, bscan);
    scan_final_kernel<<<NB_SCAN, 256, 0, stream>>>(counts, bscan, rowptr, next);
    scatter_kernel<<<edge_blocks, 256, 0, stream>>>(
        src, dst, edge_attr, next, csr_src, csr_ea);

    for (int l = 0; l < NL; ++l) {
        agg_kernel<<<agg_blocks, 256, 0, stream>>>(
            rowptr, csr_src, csr_ea, Wc16 + l*512, bc + l*64, h, h16, agg16);
        hipMemsetAsync(bn_sum, 0, 128 * sizeof(float), stream);
        // t = agg16 @ mlp1_w + b  (fp32 out) + BN stats
        mfma_gemm_kernel<true, false, false, true, false><<<mfma_blocks, 256, 0, stream>>>(
            nullptr, agg16, Wpk + (1+l)*512, mlp1_b + l*64, nullptr, nullptr,
            t, nullptr, bn_sum, bn_sumsq);
        bn_finalize_kernel<<<1, 64, 0, stream>>>(
            bn_sum, bn_sumsq, bn1_g + l*64, bn1_b + l*64, 1.0f / NN, scale, shift);
        // h = relu( relu(bn(t)) @ mlp2_w + b )  (fp32 + f16 mirror)
        mfma_gemm_kernel<false, true, true, false, true><<<mfma_blocks, 256, 0, stream>>>(
            t, nullptr, Wpk + (4+l)*512, mlp2_b + l*64, scale, shift,
            h, h16, nullptr, nullptr);
    }

    pool_kernel<<<NG, 256, 0, stream>>>(h, batch, pooled);

    hipMemsetAsync(bn_sum, 0, 128 * sizeof(float), stream);
    gemm64_kernel<0, false, true><<<NG/64, 256, 0, stream>>>(
        pooled, fo1_w, fo1_b, nullptr, nullptr, ha, NG, bn_sum, bn_sumsq);
    bn_finalize_kernel<<<1, 64, 0, stream>>>(
        bn_sum, bn_sumsq, fo_bn1_g, fo_bn1_b, 1.0f / NG, scale, shift);
    hipMemsetAsync(bn_sum, 0, 128 * sizeof(float), stream);
    gemm64_kernel<2, false, true><<<NG/64, 256, 0, stream>>>(
        ha, fo2_w, fo2_b, scale, shift, hb, NG, bn_sum, bn_sumsq);
    bn_finalize_kernel<<<1, 64, 0, stream>>>(
        bn_sum, bn_sumsq, fo_bn2_g, fo_bn2_b, 1.0f / NG, scale, shift);
    head_final_kernel<<<(NG*NC + 255)/256, 256, 0, stream>>>(
        hb, scale, shift, fo3_w, fo3_b, out);
}